// Round 14
// baseline (3681.260 us; speedup 1.0000x reference)
//
#include <hip/hip_runtime.h>
#include <hip/hip_bf16.h>
#include <stdint.h>

#define NND 100000
#define KN 32
#define NE (NND*KN)
#define BB 2048
#define TT 50
#define DD0 64
#define HH 32
#define DD2 64

__device__ __forceinline__ void tf2x32(uint32_t k0, uint32_t k1, uint32_t& x0, uint32_t& x1){
  uint32_t k2 = k0 ^ k1 ^ 0x1BD11BDAu;
#define TFR(r) { x0 += x1; x1 = (x1<<(r)) | (x1>>(32-(r))); x1 ^= x0; }
  x0 += k0; x1 += k1;
  TFR(13) TFR(15) TFR(26) TFR(6)
  x0 += k1; x1 += k2 + 1u;
  TFR(17) TFR(29) TFR(16) TFR(24)
  x0 += k2; x1 += k0 + 2u;
  TFR(13) TFR(15) TFR(26) TFR(6)
  x0 += k0; x1 += k1 + 3u;
  TFR(17) TFR(29) TFR(16) TFR(24)
  x0 += k1; x1 += k2 + 4u;
  TFR(13) TFR(15) TFR(26) TFR(6)
  x0 += k2; x1 += k0 + 5u;
#undef TFR
}

// partitionable random_bits (32-bit): elem i -> xor of both output words of tf(key,(0,i))
__device__ __forceinline__ uint32_t xorbits(uint32_t ka, uint32_t kb, uint32_t i){
  uint32_t x0=0u, x1=i;
  tf2x32(ka,kb,x0,x1);
  return x0^x1;
}

// keys layout:
//  [cid*4+0,1]=k1 (layer1 dropout), [cid*4+2,3]=k2 (layer2 dropout)  -- foldlike split of fold_in(key(42),cid)
//  [16+r*4+0,1]=randint k1, [16+r*4+2,3]=randint k2                  -- foldlike split of fold_in(key(7),2r)
__global__ void keys_kernel(uint32_t* keys){
  if(threadIdx.x==0 && blockIdx.x==0){
    for(int cid=0;cid<4;++cid){
      uint32_t K0=0u,K1=(uint32_t)cid;
      tf2x32(0u,42u,K0,K1);                        // fold_in(key(42), cid)
      uint32_t a0=0u,a1=0u; tf2x32(K0,K1,a0,a1);   // split[0] = tf(K,(0,0))
      uint32_t b0=0u,b1=1u; tf2x32(K0,K1,b0,b1);   // split[1] = tf(K,(0,1))
      keys[cid*4+0]=a0; keys[cid*4+1]=a1;
      keys[cid*4+2]=b0; keys[cid*4+3]=b1;
    }
    for(int r=0;r<2;++r){
      uint32_t F0=0u,F1=(uint32_t)(2*r);
      tf2x32(0u,7u,F0,F1);                         // kf = fold_in(key(7), 2r)
      // randint's INTERNAL split: k1,k2 = split(kf)
      uint32_t a0=0u,a1=0u; tf2x32(F0,F1,a0,a1);   // k1 = tf(kf,(0,0))
      uint32_t b0=0u,b1=1u; tf2x32(F0,F1,b0,b1);   // k2 = tf(kf,(0,1))
      keys[16+r*4+0]=a0; keys[16+r*4+1]=a1;
      keys[16+r*4+2]=b0; keys[16+r*4+3]=b1;
    }
  }
}

__global__ void count_kernel(const int* dst, int* cnt){
  int e = blockIdx.x*256 + threadIdx.x;
  if(e < NE) atomicAdd(&cnt[dst[e]], 1);
}

__global__ void scan_kernel(const int* cnt, int* off, int* cur, float* inv){
  __shared__ int part[1024];
  int t = threadIdx.x;
  const int CH = (NND + 1023)/1024;
  int lo = t*CH, hi = lo+CH; if(hi>NND) hi=NND;
  int s=0;
  for(int i=lo;i<hi;++i) s += cnt[i];
  part[t]=s;
  __syncthreads();
  if(t==0){ int run=0; for(int i=0;i<1024;++i){ int v=part[i]; part[i]=run; run+=v; } }
  __syncthreads();
  int run = part[t];
  for(int i=lo;i<hi;++i){
    off[i]=run; cur[i]=run;
    int c=cnt[i];
    inv[i]=1.0f/(float)(c>0?c:1);
    run+=c;
  }
  if(t==0) off[NND]=NE;
}

__global__ void fill_kernel(const int* dst, int* cur, int* col){
  int e = blockIdx.x*256 + threadIdx.x;
  if(e < NE){
    int d = dst[e];
    int slot = atomicAdd(&cur[d],1);
    col[slot] = e;
  }
}

__global__ void sortseg_kernel(const int* off, int* col){
  int d = blockIdx.x*256 + threadIdx.x;
  if(d < NND){
    int lo=off[d], hi=off[d+1];
    for(int i=lo+1;i<hi;++i){
      int v=col[i]; int j=i-1;
      while(j>=lo && col[j]>v){ col[j+1]=col[j]; --j; }
      col[j+1]=v;
    }
  }
}

// layer 1: h1 = dropout(leaky_relu(agg@Wl1.T + bl1 + x@Wr1.T))
__global__ void __launch_bounds__(256) sage1_kernel(const float* __restrict__ x,
    const int* __restrict__ off, const int* __restrict__ col,
    const float* __restrict__ inv, const float* __restrict__ Wl,
    const float* __restrict__ bl, const float* __restrict__ Wr,
    const uint32_t* __restrict__ keys, int cid, float* __restrict__ h1o){
  __shared__ float sWlT[DD0*HH], sWrT[DD0*HH];
  __shared__ float sA[4][DD0], sX[4][DD0];
  int t=threadIdx.x, lane=t&63, w=t>>6;
  for(int i=t;i<HH*DD0;i+=256){
    int h=i>>6, k=i&63;
    sWlT[k*HH+h]=Wl[i]; sWrT[k*HH+h]=Wr[i];
  }
  int node=blockIdx.x*4+w;
  int lo=off[node], hi=off[node+1];
  float acc=0.f;
  for(int e=lo;e<hi;++e){ int s=col[e]>>5; acc += x[(size_t)s*DD0+lane]; }
  acc *= inv[node];
  sA[w][lane]=acc;
  sX[w][lane]=x[(size_t)node*DD0+lane];
  __syncthreads();
  if(lane<HH){
    float s1=0.f, s2=0.f;
    for(int k=0;k<DD0;++k){
      s1 += sA[w][k]*sWlT[k*HH+lane];
      s2 += sX[w][k]*sWrT[k*HH+lane];
    }
    float v=s1+bl[lane]+s2;
    v = (v>=0.f) ? v : 0.01f*v;          // leaky_relu 0.01
    uint32_t j=(uint32_t)(node*HH+lane);
    uint32_t bits = xorbits(keys[cid*4+0],keys[cid*4+1],j);
    v = ((bits>>31)==0u) ? 2.f*v : 0.f;  // dropout p=0.5
    h1o[(size_t)node*HH+lane]=v;
  }
}

__device__ __forceinline__ float compute_g_row(int n, int lane,
    const float* __restrict__ h1, const int* __restrict__ off,
    const int* __restrict__ col, const float* __restrict__ inv,
    const float* __restrict__ sWlT, const float* __restrict__ sWrT,
    const float* __restrict__ bl2, uint32_t k2a, uint32_t k2b){
  int lo=off[n], hi=off[n+1];
  int d=lane&31;
  float acc=0.f;
  for(int e=lo;e<hi;++e){ int s=col[e]>>5; acc += h1[(size_t)s*HH+d]; }
  float aggd = acc*inv[n];
  float hd   = h1[(size_t)n*HH+d];
  float s1=0.f, s2=0.f;
  for(int k=0;k<HH;++k){
    float ak=__shfl(aggd,k,64);
    float hk=__shfl(hd,k,64);
    s1 += ak*sWlT[k*DD2+lane];
    s2 += hk*sWrT[k*DD2+lane];
  }
  float v=s1+bl2[lane]+s2;
  uint32_t j=(uint32_t)n*64u+(uint32_t)lane;
  uint32_t bits = xorbits(k2a,k2b,j);
  v = ((bits>>31)==0u) ? 2.f*v : 0.f;
  float ss=v*v;
  for(int m=1;m<64;m<<=1) ss += __shfl_xor(ss,m,64);
  return v/fmaxf(sqrtf(ss),1e-12f);
}

__global__ void __launch_bounds__(256) fstep1_kernel(
    const float* __restrict__ h1, const int* __restrict__ off,
    const int* __restrict__ col, const float* __restrict__ inv,
    const float* __restrict__ Wl2, const float* __restrict__ bl2,
    const float* __restrict__ Wr2, const uint32_t* __restrict__ keys, int cid,
    const int* __restrict__ users, const int* __restrict__ pid_arr,
    const int* __restrict__ adj, int* __restrict__ oh_out, float* __restrict__ l1_out){
  __shared__ float sWlT[HH*DD2], sWrT[HH*DD2];
  __shared__ float rows[2+KN][DD2];
  __shared__ int nds[2+KN];
  __shared__ float ps[KN];
  int t=threadIdx.x, lane=t&63, w=t>>6, b=blockIdx.x;
  for(int i=t;i<DD2*HH;i+=256){
    int d=i>>5, k=i&31;
    sWlT[k*DD2+d]=Wl2[i]; sWrT[k*DD2+d]=Wr2[i];
  }
  if(t==0){ nds[0]=users[b]; nds[1]=pid_arr[b]; }
  if(t>=2 && t<2+KN) nds[t]=adj[(size_t)pid_arr[b]*KN + (t-2)];
  __syncthreads();
  uint32_t k2a=keys[cid*4+2], k2b=keys[cid*4+3];
  for(int r=w; r<2+KN; r+=4)
    rows[r][lane]=compute_g_row(nds[r],lane,h1,off,col,inv,sWlT,sWrT,bl2,k2a,k2b);
  __syncthreads();
  if(t<KN){
    float p=0.f;
    for(int d=0;d<DD2;++d) p += rows[2+t][d]*(rows[0][d]*rows[1][d]);
    ps[t]=p;
  }
  __syncthreads();
  if(t==0){
    float m=ps[0]; for(int k=1;k<KN;++k) m=fmaxf(m,ps[k]);
    float s=0.f;  for(int k=0;k<KN;++k) s += expf(ps[k]-m);
    int best=0; float bv=ps[0];
    for(int k=1;k<KN;++k) if(ps[k]>bv){bv=ps[k];best=k;}   // first-max = jnp.argmax
    oh_out[b]=nds[2+best];
    l1_out[b]=(ps[best]-m)-logf(s);
  }
}

__global__ void __launch_bounds__(256) fstep2_kernel(
    const float* __restrict__ h1, const int* __restrict__ off,
    const int* __restrict__ col, const float* __restrict__ inv,
    const float* __restrict__ Wl2, const float* __restrict__ bl2,
    const float* __restrict__ Wr2, const uint32_t* __restrict__ keys,
    int cid, int kf_idx,
    const int* __restrict__ users, const int* __restrict__ oh,
    const int* __restrict__ adj,
    const float* __restrict__ du, const float* __restrict__ di,
    const int* __restrict__ train, const int* __restrict__ neg,
    const float* __restrict__ l1, int round,
    int* __restrict__ gneg_out, float* __restrict__ out){
  __shared__ float sWlT[HH*DD2], sWrT[HH*DD2];
  __shared__ float rows[2+KN][DD2];
  __shared__ int nds[2+KN];
  __shared__ float ps[KN], lps[KN], rk[KN];
  __shared__ int nid[KN], cand[KN];
  __shared__ float msh[2];
  int t=threadIdx.x, lane=t&63, w=t>>6, b=blockIdx.x;
  for(int i=t;i<DD2*HH;i+=256){
    int d=i>>5, k=i&31;
    sWlT[k*DD2+d]=Wl2[i]; sWrT[k*DD2+d]=Wr2[i];
  }
  if(t==0){ nds[0]=users[b]; nds[1]=oh[b]; }
  if(t>=2 && t<2+KN) nds[t]=adj[(size_t)oh[b]*KN + (t-2)];
  __syncthreads();
  uint32_t k2a=keys[cid*4+2], k2b=keys[cid*4+3];
  for(int r=w; r<2+KN; r+=4)
    rows[r][lane]=compute_g_row(nds[r],lane,h1,off,col,inv,sWlT,sWrT,bl2,k2a,k2b);
  __syncthreads();
  if(t<KN){
    float p=0.f;
    for(int d=0;d<DD2;++d) p += rows[2+t][d]*(rows[0][d]*rows[1][d]);
    ps[t]=p;
  }
  __syncthreads();
  if(t==0){
    float m=ps[0]; for(int k=1;k<KN;++k) m=fmaxf(m,ps[k]);
    float s=0.f;  for(int k=0;k<KN;++k) s += expf(ps[k]-m);
    msh[0]=m; msh[1]=logf(s);
    for(int k=0;k<KN;++k) nid[k]=k;
    for(int i=1;i<KN;++i){                       // stable ascending = jnp.argsort
      int v=nid[i]; float pv=ps[v]; int j=i-1;
      while(j>=0 && ps[nid[j]]>pv){ nid[j+1]=nid[j]; --j; }
      nid[j+1]=v;
    }
  }
  __syncthreads();
  if(t<KN){
    int n=t, c=nds[2+nid[n]];
    if(c<0 || c>49999){
      // jax randint INTERNALLY SPLITS: k1,k2 = split(kf); hi=bits(k1,i), lo=bits(k2,i)
      uint32_t i0=(uint32_t)(b*KN+n);
      const uint32_t* fk = keys + 16 + kf_idx*4;
      uint32_t hb = xorbits(fk[0], fk[1], i0);
      uint32_t lb = xorbits(fk[2], fk[3], i0);
      c=(int)(((hb%50000u)*17296u + (lb%50000u))%50000u);   // 17296 = (2^16%50000)^2 % 50000
    }
    cand[n]=c;
    lps[n]=(ps[nid[n]]-msh[0])-msh[1];
    int u=nds[0];
    float rr=0.f;
    for(int d=0;d<DD2;++d) rr += du[(size_t)u*DD2+d]*di[(size_t)c*DD2+d];
    rk[n]=rr;
  }
  __syncthreads();
  if(t==0){
    int best=0; float bv=rk[0];
    for(int n=1;n<KN;++n) if(rk[n]>bv){bv=rk[n];best=n;}
    int gn=cand[best]; float lsel=lps[best];
    bool it=false;
    for(int t2=0;t2<TT;++t2) if(train[(size_t)b*TT+t2]==gn){it=true;break;}
    if(it) gn=neg[b];
    gneg_out[b]=gn;
    out[b*2+round]        = (float)gn;
    out[BB*2 + b*2+round] = l1[b]+lsel;
  }
}

extern "C" void kernel_launch(void* const* d_in, const int* in_sizes, int n_in,
                              void* d_out, int out_size, void* d_ws, size_t ws_size,
                              hipStream_t stream) {
  const int*   users=(const int*)d_in[0];
  const int*   pos  =(const int*)d_in[1];
  const int*   neg  =(const int*)d_in[2];
  const int*   train=(const int*)d_in[3];
  const int*   adj  =(const int*)d_in[4];
  const int*   edge =(const int*)d_in[5];
  const float* ent  =(const float*)d_in[6];
  const float* Wl1  =(const float*)d_in[7];
  const float* bl1  =(const float*)d_in[8];
  const float* Wr1  =(const float*)d_in[9];
  const float* Wl2  =(const float*)d_in[10];
  const float* bl2  =(const float*)d_in[11];
  const float* Wr2  =(const float*)d_in[12];
  const float* du   =(const float*)d_in[13];
  const float* di   =(const float*)d_in[14];
  float* out=(float*)d_out;

  char* wsb=(char*)d_ws;
  size_t o=0;
  auto alloc=[&](size_t n)->char*{ char* p=wsb+o; o=(o+n+255)&~(size_t)255; return p; };
  uint32_t* keys=(uint32_t*)alloc(32*4);
  int*   ohb=(int*)alloc((size_t)BB*4);
  float* l1b=(float*)alloc((size_t)BB*4);
  int*   g1b=(int*)alloc((size_t)BB*4);
  int*   g2b=(int*)alloc((size_t)BB*4);
  int*   cnt=(int*)alloc((size_t)NND*4);
  int*   off=(int*)alloc((size_t)(NND+1)*4);
  int*   cur=(int*)alloc((size_t)NND*4);
  float* inv=(float*)alloc((size_t)NND*4);
  int*   col=(int*)alloc((size_t)NE*4);
  float* h1 =(float*)alloc((size_t)NND*HH*4);

  hipMemsetAsync(cnt,0,(size_t)NND*4,stream);
  keys_kernel<<<1,64,0,stream>>>(keys);

  count_kernel<<<NE/256,256,0,stream>>>(edge,cnt);
  scan_kernel<<<1,1024,0,stream>>>(cnt,off,cur,inv);
  fill_kernel<<<NE/256,256,0,stream>>>(edge,cur,col);
  sortseg_kernel<<<(NND+255)/256,256,0,stream>>>(off,col);

  for(int r=0;r<2;++r){
    const int* pid = (r==0)? pos : g1b;
    int cidA=2*r, cidB=2*r+1;
    sage1_kernel<<<NND/4,256,0,stream>>>(ent,off,col,inv,Wl1,bl1,Wr1,keys,cidA,h1);
    fstep1_kernel<<<BB,256,0,stream>>>(h1,off,col,inv,Wl2,bl2,Wr2,keys,cidA,
                                       users,pid,adj,ohb,l1b);
    sage1_kernel<<<NND/4,256,0,stream>>>(ent,off,col,inv,Wl1,bl1,Wr1,keys,cidB,h1);
    fstep2_kernel<<<BB,256,0,stream>>>(h1,off,col,inv,Wl2,bl2,Wr2,keys,cidB,r,
                                       users,ohb,adj,du,di,train,neg,l1b,r,
                                       (r==0)?g1b:g2b,out);
  }
}

// Round 15
// 2565.023 us; speedup vs baseline: 1.4352x; 1.4352x over previous
//
#include <hip/hip_runtime.h>
#include <hip/hip_bf16.h>
#include <stdint.h>

#define NND 100000
#define KN 32
#define NE (NND*KN)
#define BB 2048
#define TT 50
#define DD0 64
#define HH 32
#define DD2 64
#define NROWS 34

__device__ __forceinline__ void tf2x32(uint32_t k0, uint32_t k1, uint32_t& x0, uint32_t& x1){
  uint32_t k2 = k0 ^ k1 ^ 0x1BD11BDAu;
#define TFR(r) { x0 += x1; x1 = (x1<<(r)) | (x1>>(32-(r))); x1 ^= x0; }
  x0 += k0; x1 += k1;
  TFR(13) TFR(15) TFR(26) TFR(6)
  x0 += k1; x1 += k2 + 1u;
  TFR(17) TFR(29) TFR(16) TFR(24)
  x0 += k2; x1 += k0 + 2u;
  TFR(13) TFR(15) TFR(26) TFR(6)
  x0 += k0; x1 += k1 + 3u;
  TFR(17) TFR(29) TFR(16) TFR(24)
  x0 += k1; x1 += k2 + 4u;
  TFR(13) TFR(15) TFR(26) TFR(6)
  x0 += k2; x1 += k0 + 5u;
#undef TFR
}

__device__ __forceinline__ uint32_t xorbits(uint32_t ka, uint32_t kb, uint32_t i){
  uint32_t x0=0u, x1=i;
  tf2x32(ka,kb,x0,x1);
  return x0^x1;
}

// keys layout:
//  [cid*4+0,1]=k1 (layer1 dropout), [cid*4+2,3]=k2 (layer2 dropout)
//  [16+r*4+0,1]=randint k1, [16+r*4+2,3]=randint k2
__global__ void keys_kernel(uint32_t* keys){
  if(threadIdx.x==0 && blockIdx.x==0){
    for(int cid=0;cid<4;++cid){
      uint32_t K0=0u,K1=(uint32_t)cid;
      tf2x32(0u,42u,K0,K1);
      uint32_t a0=0u,a1=0u; tf2x32(K0,K1,a0,a1);
      uint32_t b0=0u,b1=1u; tf2x32(K0,K1,b0,b1);
      keys[cid*4+0]=a0; keys[cid*4+1]=a1;
      keys[cid*4+2]=b0; keys[cid*4+3]=b1;
    }
    for(int r=0;r<2;++r){
      uint32_t F0=0u,F1=(uint32_t)(2*r);
      tf2x32(0u,7u,F0,F1);
      uint32_t a0=0u,a1=0u; tf2x32(F0,F1,a0,a1);
      uint32_t b0=0u,b1=1u; tf2x32(F0,F1,b0,b1);
      keys[16+r*4+0]=a0; keys[16+r*4+1]=a1;
      keys[16+r*4+2]=b0; keys[16+r*4+3]=b1;
    }
  }
}

__global__ void count_kernel(const int* dst, int* cnt){
  int e = blockIdx.x*256 + threadIdx.x;
  if(e < NE) atomicAdd(&cnt[dst[e]], 1);
}

__global__ void scan_kernel(const int* cnt, int* off, int* cur, float* inv){
  __shared__ int part[1024];
  int t = threadIdx.x;
  const int CH = (NND + 1023)/1024;
  int lo = t*CH, hi = lo+CH; if(hi>NND) hi=NND;
  int s=0;
  for(int i=lo;i<hi;++i) s += cnt[i];
  part[t]=s;
  __syncthreads();
  if(t==0){ int run=0; for(int i=0;i<1024;++i){ int v=part[i]; part[i]=run; run+=v; } }
  __syncthreads();
  int run = part[t];
  for(int i=lo;i<hi;++i){
    off[i]=run; cur[i]=run;
    int c=cnt[i];
    inv[i]=1.0f/(float)(c>0?c:1);
    run+=c;
  }
  if(t==0) off[NND]=NE;
}

__global__ void fill_kernel(const int* dst, int* cur, int* col){
  int e = blockIdx.x*256 + threadIdx.x;
  if(e < NE){
    int d = dst[e];
    int slot = atomicAdd(&cur[d],1);
    col[slot] = e;
  }
}

__global__ void sortseg_kernel(const int* off, int* col){
  int d = blockIdx.x*256 + threadIdx.x;
  if(d < NND){
    int lo=off[d], hi=off[d+1];
    for(int i=lo+1;i<hi;++i){
      int v=col[i]; int j=i-1;
      while(j>=lo && col[j]>v){ col[j+1]=col[j]; --j; }
      col[j+1]=v;
    }
  }
}

// order-preserving batched gather: acc += sum over edges e in [lo,hi) of src[(col[e]>>5)*S + d]
// (sequential-add order identical to a simple loop; up to 8 loads in flight)
__device__ __forceinline__ float gather_seq(const float* __restrict__ src, int S, int d,
    const int* __restrict__ col, int lo, int hi, int lane){
  float acc=0.f;
  int deg=hi-lo, base=0;
  while(base<deg){
    int rem=deg-base; int cw = rem<64?rem:64;
    int cv = col[lo+base+ (lane<cw?lane:cw-1)];
    for(int k=0;k<cw;k+=8){
      int m=cw-k;
      float v0,v1,v2,v3,v4,v5,v6,v7;
      { int q=k;                 int s=__shfl(cv,q,64)>>5; v0=src[(size_t)s*S+d]; }
      { int q=(1<m)?k+1:k;       int s=__shfl(cv,q,64)>>5; v1=src[(size_t)s*S+d]; }
      { int q=(2<m)?k+2:k;       int s=__shfl(cv,q,64)>>5; v2=src[(size_t)s*S+d]; }
      { int q=(3<m)?k+3:k;       int s=__shfl(cv,q,64)>>5; v3=src[(size_t)s*S+d]; }
      { int q=(4<m)?k+4:k;       int s=__shfl(cv,q,64)>>5; v4=src[(size_t)s*S+d]; }
      { int q=(5<m)?k+5:k;       int s=__shfl(cv,q,64)>>5; v5=src[(size_t)s*S+d]; }
      { int q=(6<m)?k+6:k;       int s=__shfl(cv,q,64)>>5; v6=src[(size_t)s*S+d]; }
      { int q=(7<m)?k+7:k;       int s=__shfl(cv,q,64)>>5; v7=src[(size_t)s*S+d]; }
      acc+=v0;
      if(m>1)acc+=v1; if(m>2)acc+=v2; if(m>3)acc+=v3;
      if(m>4)acc+=v4; if(m>5)acc+=v5; if(m>6)acc+=v6; if(m>7)acc+=v7;
    }
    base+=cw;
  }
  return acc;
}

// layer 1: h1 = dropout(leaky_relu(agg@Wl1.T + bl1 + x@Wr1.T))
__global__ void __launch_bounds__(256) sage1_kernel(const float* __restrict__ x,
    const int* __restrict__ off, const int* __restrict__ col,
    const float* __restrict__ inv, const float* __restrict__ Wl,
    const float* __restrict__ bl, const float* __restrict__ Wr,
    const uint32_t* __restrict__ keys, int cid, float* __restrict__ h1o){
  __shared__ float sWlT[DD0*HH], sWrT[DD0*HH];   // sWlT[k*32+h] = Wl[h][k]
  __shared__ float sA[4][DD0], sX[4][DD0];
  int t=threadIdx.x, lane=t&63, w=t>>6;
  for(int j=t;j<HH*DD0;j+=256){                  // conflict-free staging (consecutive writes)
    int k=j>>5, h=j&31;
    sWlT[j]=Wl[h*DD0+k]; sWrT[j]=Wr[h*DD0+k];
  }
  int node=blockIdx.x*4+w;                       // grid = NND/4 exactly
  int lo=off[node], hi=off[node+1];
  float acc=gather_seq(x,DD0,lane,col,lo,hi,lane);
  acc *= inv[node];
  sA[w][lane]=acc;
  sX[w][lane]=x[(size_t)node*DD0+lane];
  __syncthreads();
  if(lane<HH){
    float s1=0.f, s2=0.f;
    for(int k=0;k<DD0;++k){
      s1 += sA[w][k]*sWlT[k*HH+lane];
      s2 += sX[w][k]*sWrT[k*HH+lane];
    }
    float v=s1+bl[lane]+s2;
    v = (v>=0.f) ? v : 0.01f*v;          // leaky_relu 0.01
    uint32_t j=(uint32_t)(node*HH+lane);
    uint32_t bits = xorbits(keys[cid*4+0],keys[cid*4+1],j);
    v = ((bits>>31)==0u) ? 2.f*v : 0.f;  // dropout p=0.5
    h1o[(size_t)node*HH+lane]=v;
  }
}

// one normalized g-row for node n, full wave; sW*T[k*64+d] = W*2[d][k]
__device__ __forceinline__ float g_row_core(int n, int lane,
    const float* __restrict__ h1, const int* __restrict__ off,
    const int* __restrict__ col, const float* __restrict__ inv,
    const float* __restrict__ sWlT, const float* __restrict__ sWrT,
    const float* __restrict__ bl2, uint32_t k2a, uint32_t k2b){
  int lo=off[n], hi=off[n+1];
  int d=lane&31;
  float acc=gather_seq(h1,HH,d,col,lo,hi,lane);
  float aggd = acc*inv[n];
  float hd   = h1[(size_t)n*HH+d];
  float s1=0.f, s2=0.f;
  for(int k=0;k<HH;++k){
    float ak=__shfl(aggd,k,64);
    float hk=__shfl(hd,k,64);
    s1 += ak*sWlT[k*DD2+lane];
    s2 += hk*sWrT[k*DD2+lane];
  }
  float v=s1+bl2[lane]+s2;
  uint32_t j=(uint32_t)n*64u+(uint32_t)lane;
  uint32_t bits = xorbits(k2a,k2b,j);
  v = ((bits>>31)==0u) ? 2.f*v : 0.f;
  float ss=v*v;
  for(int m=1;m<64;m<<=1) ss += __shfl_xor(ss,m,64);
  return v/fmaxf(sqrtf(ss),1e-12f);
}

// ===== optimized path: one wave per g-row =====
// grid = BB*NROWS/4 blocks of 256; row r: 0=user, 1=pid, 2..33=adj[pid]
__global__ void __launch_bounds__(256) grows_kernel(
    const float* __restrict__ h1, const int* __restrict__ off,
    const int* __restrict__ col, const float* __restrict__ inv,
    const float* __restrict__ Wl2, const float* __restrict__ bl2,
    const float* __restrict__ Wr2, const uint32_t* __restrict__ keys, int cid,
    const int* __restrict__ users, const int* __restrict__ pid_arr,
    const int* __restrict__ adj, float* __restrict__ rowbuf){
  __shared__ float sWlT[HH*DD2], sWrT[HH*DD2];
  int t=threadIdx.x, lane=t&63, w=t>>6;
  for(int j=t;j<HH*DD2;j+=256){                  // conflict-free staging
    int k=j>>6, d=j&63;
    sWlT[j]=Wl2[d*HH+k]; sWrT[j]=Wr2[d*HH+k];
  }
  __syncthreads();
  int wg = blockIdx.x*4 + w;                     // wg in [0, BB*NROWS)
  int b = wg/NROWS, r = wg - b*NROWS;
  int pid = pid_arr[b];
  int node = (r==0)? users[b] : ((r==1)? pid : adj[(size_t)pid*KN + (r-2)]);
  uint32_t k2a=keys[cid*4+2], k2b=keys[cid*4+3];
  float v = g_row_core(node,lane,h1,off,col,inv,sWlT,sWrT,bl2,k2a,k2b);
  rowbuf[(size_t)wg*DD2 + lane] = v;
}

__global__ void __launch_bounds__(64) sel1_kernel(
    const float* __restrict__ rowbuf,
    const int* __restrict__ users, const int* __restrict__ pid_arr,
    const int* __restrict__ adj, int* __restrict__ oh_out, float* __restrict__ l1_out){
  int b=blockIdx.x, t=threadIdx.x;
  __shared__ float wsh[DD2];
  __shared__ float ps[KN];
  const float* rb = rowbuf + (size_t)b*NROWS*DD2;
  wsh[t] = rb[t]*rb[DD2+t];
  __syncthreads();
  if(t<KN){
    float p=0.f;
    const float* rr = rb + (size_t)(2+t)*DD2;
    for(int d=0;d<DD2;++d) p += rr[d]*wsh[d];
    ps[t]=p;
  }
  __syncthreads();
  if(t==0){
    float m=ps[0]; for(int k=1;k<KN;++k) m=fmaxf(m,ps[k]);
    float s=0.f;  for(int k=0;k<KN;++k) s += expf(ps[k]-m);
    int best=0; float bv=ps[0];
    for(int k=1;k<KN;++k) if(ps[k]>bv){bv=ps[k];best=k;}
    oh_out[b]=adj[(size_t)pid_arr[b]*KN+best];
    l1_out[b]=(ps[best]-m)-logf(s);
  }
}

__global__ void __launch_bounds__(64) sel2_kernel(
    const float* __restrict__ rowbuf, const uint32_t* __restrict__ keys, int kf_idx,
    const int* __restrict__ users, const int* __restrict__ oh,
    const int* __restrict__ adj,
    const float* __restrict__ du, const float* __restrict__ di,
    const int* __restrict__ train, const int* __restrict__ neg,
    const float* __restrict__ l1, int round,
    int* __restrict__ gneg_out, float* __restrict__ out){
  int b=blockIdx.x, t=threadIdx.x;
  __shared__ float wsh[DD2];
  __shared__ float ps[KN], lps[KN], rk[KN];
  __shared__ int nid[KN], cand[KN];
  __shared__ float msh[2];
  const float* rb = rowbuf + (size_t)b*NROWS*DD2;
  wsh[t] = rb[t]*rb[DD2+t];
  __syncthreads();
  if(t<KN){
    float p=0.f;
    const float* rr = rb + (size_t)(2+t)*DD2;
    for(int d=0;d<DD2;++d) p += rr[d]*wsh[d];
    ps[t]=p;
  }
  __syncthreads();
  if(t==0){
    float m=ps[0]; for(int k=1;k<KN;++k) m=fmaxf(m,ps[k]);
    float s=0.f;  for(int k=0;k<KN;++k) s += expf(ps[k]-m);
    msh[0]=m; msh[1]=logf(s);
    for(int k=0;k<KN;++k) nid[k]=k;
    for(int i=1;i<KN;++i){                       // stable ascending = jnp.argsort
      int v=nid[i]; float pv=ps[v]; int j=i-1;
      while(j>=0 && ps[nid[j]]>pv){ nid[j+1]=nid[j]; --j; }
      nid[j+1]=v;
    }
  }
  __syncthreads();
  if(t<KN){
    int n=t, c=adj[(size_t)oh[b]*KN + nid[n]];
    if(c<0 || c>49999){
      uint32_t i0=(uint32_t)(b*KN+n);
      const uint32_t* fk = keys + 16 + kf_idx*4;
      uint32_t hb = xorbits(fk[0], fk[1], i0);
      uint32_t lb = xorbits(fk[2], fk[3], i0);
      c=(int)(((hb%50000u)*17296u + (lb%50000u))%50000u);
    }
    cand[n]=c;
    lps[n]=(ps[nid[n]]-msh[0])-msh[1];
    int u=users[b];
    float rr=0.f;
    for(int d=0;d<DD2;++d) rr += du[(size_t)u*DD2+d]*di[(size_t)c*DD2+d];
    rk[n]=rr;
  }
  __syncthreads();
  if(t==0){
    int best=0; float bv=rk[0];
    for(int n=1;n<KN;++n) if(rk[n]>bv){bv=rk[n];best=n;}
    int gn=cand[best]; float lsel=lps[best];
    bool it=false;
    for(int t2=0;t2<TT;++t2) if(train[(size_t)b*TT+t2]==gn){it=true;break;}
    if(it) gn=neg[b];
    gneg_out[b]=gn;
    out[b*2+round]        = (float)gn;
    out[BB*2 + b*2+round] = l1[b]+lsel;
  }
}

// ===== fallback path (R14 structure, used only if ws too small) =====
__global__ void __launch_bounds__(256) fstep1_kernel(
    const float* __restrict__ h1, const int* __restrict__ off,
    const int* __restrict__ col, const float* __restrict__ inv,
    const float* __restrict__ Wl2, const float* __restrict__ bl2,
    const float* __restrict__ Wr2, const uint32_t* __restrict__ keys, int cid,
    const int* __restrict__ users, const int* __restrict__ pid_arr,
    const int* __restrict__ adj, int* __restrict__ oh_out, float* __restrict__ l1_out){
  __shared__ float sWlT[HH*DD2], sWrT[HH*DD2];
  __shared__ float rows[2+KN][DD2+1];
  __shared__ int nds[2+KN];
  __shared__ float ps[KN];
  int t=threadIdx.x, lane=t&63, w=t>>6, b=blockIdx.x;
  for(int j=t;j<HH*DD2;j+=256){
    int k=j>>6, d=j&63;
    sWlT[j]=Wl2[d*HH+k]; sWrT[j]=Wr2[d*HH+k];
  }
  if(t==0){ nds[0]=users[b]; nds[1]=pid_arr[b]; }
  if(t>=2 && t<2+KN) nds[t]=adj[(size_t)pid_arr[b]*KN + (t-2)];
  __syncthreads();
  uint32_t k2a=keys[cid*4+2], k2b=keys[cid*4+3];
  for(int r=w; r<2+KN; r+=4)
    rows[r][lane]=g_row_core(nds[r],lane,h1,off,col,inv,sWlT,sWrT,bl2,k2a,k2b);
  __syncthreads();
  if(t<KN){
    float p=0.f;
    for(int d=0;d<DD2;++d) p += rows[2+t][d]*(rows[0][d]*rows[1][d]);
    ps[t]=p;
  }
  __syncthreads();
  if(t==0){
    float m=ps[0]; for(int k=1;k<KN;++k) m=fmaxf(m,ps[k]);
    float s=0.f;  for(int k=0;k<KN;++k) s += expf(ps[k]-m);
    int best=0; float bv=ps[0];
    for(int k=1;k<KN;++k) if(ps[k]>bv){bv=ps[k];best=k;}
    oh_out[b]=nds[2+best];
    l1_out[b]=(ps[best]-m)-logf(s);
  }
}

__global__ void __launch_bounds__(256) fstep2_kernel(
    const float* __restrict__ h1, const int* __restrict__ off,
    const int* __restrict__ col, const float* __restrict__ inv,
    const float* __restrict__ Wl2, const float* __restrict__ bl2,
    const float* __restrict__ Wr2, const uint32_t* __restrict__ keys,
    int cid, int kf_idx,
    const int* __restrict__ users, const int* __restrict__ oh,
    const int* __restrict__ adj,
    const float* __restrict__ du, const float* __restrict__ di,
    const int* __restrict__ train, const int* __restrict__ neg,
    const float* __restrict__ l1, int round,
    int* __restrict__ gneg_out, float* __restrict__ out){
  __shared__ float sWlT[HH*DD2], sWrT[HH*DD2];
  __shared__ float rows[2+KN][DD2+1];
  __shared__ int nds[2+KN];
  __shared__ float ps[KN], lps[KN], rk[KN];
  __shared__ int nid[KN], cand[KN];
  __shared__ float msh[2];
  int t=threadIdx.x, lane=t&63, w=t>>6, b=blockIdx.x;
  for(int j=t;j<HH*DD2;j+=256){
    int k=j>>6, d=j&63;
    sWlT[j]=Wl2[d*HH+k]; sWrT[j]=Wr2[d*HH+k];
  }
  if(t==0){ nds[0]=users[b]; nds[1]=oh[b]; }
  if(t>=2 && t<2+KN) nds[t]=adj[(size_t)oh[b]*KN + (t-2)];
  __syncthreads();
  uint32_t k2a=keys[cid*4+2], k2b=keys[cid*4+3];
  for(int r=w; r<2+KN; r+=4)
    rows[r][lane]=g_row_core(nds[r],lane,h1,off,col,inv,sWlT,sWrT,bl2,k2a,k2b);
  __syncthreads();
  if(t<KN){
    float p=0.f;
    for(int d=0;d<DD2;++d) p += rows[2+t][d]*(rows[0][d]*rows[1][d]);
    ps[t]=p;
  }
  __syncthreads();
  if(t==0){
    float m=ps[0]; for(int k=1;k<KN;++k) m=fmaxf(m,ps[k]);
    float s=0.f;  for(int k=0;k<KN;++k) s += expf(ps[k]-m);
    msh[0]=m; msh[1]=logf(s);
    for(int k=0;k<KN;++k) nid[k]=k;
    for(int i=1;i<KN;++i){
      int v=nid[i]; float pv=ps[v]; int j=i-1;
      while(j>=0 && ps[nid[j]]>pv){ nid[j+1]=nid[j]; --j; }
      nid[j+1]=v;
    }
  }
  __syncthreads();
  if(t<KN){
    int n=t, c=nds[2+nid[n]];
    if(c<0 || c>49999){
      uint32_t i0=(uint32_t)(b*KN+n);
      const uint32_t* fk = keys + 16 + kf_idx*4;
      uint32_t hb = xorbits(fk[0], fk[1], i0);
      uint32_t lb = xorbits(fk[2], fk[3], i0);
      c=(int)(((hb%50000u)*17296u + (lb%50000u))%50000u);
    }
    cand[n]=c;
    lps[n]=(ps[nid[n]]-msh[0])-msh[1];
    int u=nds[0];
    float rr=0.f;
    for(int d=0;d<DD2;++d) rr += du[(size_t)u*DD2+d]*di[(size_t)c*DD2+d];
    rk[n]=rr;
  }
  __syncthreads();
  if(t==0){
    int best=0; float bv=rk[0];
    for(int n=1;n<KN;++n) if(rk[n]>bv){bv=rk[n];best=n;}
    int gn=cand[best]; float lsel=lps[best];
    bool it=false;
    for(int t2=0;t2<TT;++t2) if(train[(size_t)b*TT+t2]==gn){it=true;break;}
    if(it) gn=neg[b];
    gneg_out[b]=gn;
    out[b*2+round]        = (float)gn;
    out[BB*2 + b*2+round] = l1[b]+lsel;
  }
}

extern "C" void kernel_launch(void* const* d_in, const int* in_sizes, int n_in,
                              void* d_out, int out_size, void* d_ws, size_t ws_size,
                              hipStream_t stream) {
  const int*   users=(const int*)d_in[0];
  const int*   pos  =(const int*)d_in[1];
  const int*   neg  =(const int*)d_in[2];
  const int*   train=(const int*)d_in[3];
  const int*   adj  =(const int*)d_in[4];
  const int*   edge =(const int*)d_in[5];
  const float* ent  =(const float*)d_in[6];
  const float* Wl1  =(const float*)d_in[7];
  const float* bl1  =(const float*)d_in[8];
  const float* Wr1  =(const float*)d_in[9];
  const float* Wl2  =(const float*)d_in[10];
  const float* bl2  =(const float*)d_in[11];
  const float* Wr2  =(const float*)d_in[12];
  const float* du   =(const float*)d_in[13];
  const float* di   =(const float*)d_in[14];
  float* out=(float*)d_out;

  char* wsb=(char*)d_ws;
  size_t o=0;
  auto alloc=[&](size_t n)->char*{ char* p=wsb+o; o=(o+n+255)&~(size_t)255; return p; };
  uint32_t* keys=(uint32_t*)alloc(32*4);
  int*   ohb=(int*)alloc((size_t)BB*4);
  float* l1b=(float*)alloc((size_t)BB*4);
  int*   g1b=(int*)alloc((size_t)BB*4);
  int*   g2b=(int*)alloc((size_t)BB*4);
  int*   cnt=(int*)alloc((size_t)NND*4);
  int*   off=(int*)alloc((size_t)(NND+1)*4);
  int*   cur=(int*)alloc((size_t)NND*4);
  float* inv=(float*)alloc((size_t)NND*4);
  int*   col=(int*)alloc((size_t)NE*4);
  float* h1 =(float*)alloc((size_t)NND*HH*4);
  size_t o_small = o;
  float* rowbuf=(float*)alloc((size_t)BB*NROWS*DD2*4);
  bool big = (ws_size >= o);
  if(!big){ rowbuf=nullptr; }

  hipMemsetAsync(cnt,0,(size_t)NND*4,stream);
  keys_kernel<<<1,64,0,stream>>>(keys);

  count_kernel<<<NE/256,256,0,stream>>>(edge,cnt);
  scan_kernel<<<1,1024,0,stream>>>(cnt,off,cur,inv);
  fill_kernel<<<NE/256,256,0,stream>>>(edge,cur,col);
  sortseg_kernel<<<(NND+255)/256,256,0,stream>>>(off,col);

  const int GROWS_GRID = BB*NROWS/4;   // 17408

  for(int r=0;r<2;++r){
    const int* pid = (r==0)? pos : g1b;
    int cidA=2*r, cidB=2*r+1;
    sage1_kernel<<<NND/4,256,0,stream>>>(ent,off,col,inv,Wl1,bl1,Wr1,keys,cidA,h1);
    if(big){
      grows_kernel<<<GROWS_GRID,256,0,stream>>>(h1,off,col,inv,Wl2,bl2,Wr2,keys,cidA,
                                                users,pid,adj,rowbuf);
      sel1_kernel<<<BB,64,0,stream>>>(rowbuf,users,pid,adj,ohb,l1b);
    } else {
      fstep1_kernel<<<BB,256,0,stream>>>(h1,off,col,inv,Wl2,bl2,Wr2,keys,cidA,
                                         users,pid,adj,ohb,l1b);
    }
    sage1_kernel<<<NND/4,256,0,stream>>>(ent,off,col,inv,Wl1,bl1,Wr1,keys,cidB,h1);
    if(big){
      grows_kernel<<<GROWS_GRID,256,0,stream>>>(h1,off,col,inv,Wl2,bl2,Wr2,keys,cidB,
                                                users,ohb,adj,rowbuf);
      sel2_kernel<<<BB,64,0,stream>>>(rowbuf,keys,r,users,ohb,adj,du,di,train,neg,l1b,r,
                                      (r==0)?g1b:g2b,out);
    } else {
      fstep2_kernel<<<BB,256,0,stream>>>(h1,off,col,inv,Wl2,bl2,Wr2,keys,cidB,r,
                                         users,ohb,adj,du,di,train,neg,l1b,r,
                                         (r==0)?g1b:g2b,out);
    }
  }
  (void)o_small;
}

// Round 16
// 1913.808 us; speedup vs baseline: 1.9235x; 1.3403x over previous
//
#include <hip/hip_runtime.h>
#include <hip/hip_bf16.h>
#include <stdint.h>

#define NND 100000
#define KN 32
#define NE (NND*KN)
#define BB 2048
#define TT 50
#define DD0 64
#define HH 32
#define DD2 64
#define NROWS 34

__device__ __forceinline__ void tf2x32(uint32_t k0, uint32_t k1, uint32_t& x0, uint32_t& x1){
  uint32_t k2 = k0 ^ k1 ^ 0x1BD11BDAu;
#define TFR(r) { x0 += x1; x1 = (x1<<(r)) | (x1>>(32-(r))); x1 ^= x0; }
  x0 += k0; x1 += k1;
  TFR(13) TFR(15) TFR(26) TFR(6)
  x0 += k1; x1 += k2 + 1u;
  TFR(17) TFR(29) TFR(16) TFR(24)
  x0 += k2; x1 += k0 + 2u;
  TFR(13) TFR(15) TFR(26) TFR(6)
  x0 += k0; x1 += k1 + 3u;
  TFR(17) TFR(29) TFR(16) TFR(24)
  x0 += k1; x1 += k2 + 4u;
  TFR(13) TFR(15) TFR(26) TFR(6)
  x0 += k2; x1 += k0 + 5u;
#undef TFR
}

__device__ __forceinline__ uint32_t xorbits(uint32_t ka, uint32_t kb, uint32_t i){
  uint32_t x0=0u, x1=i;
  tf2x32(ka,kb,x0,x1);
  return x0^x1;
}

// keys layout:
//  [cid*4+0,1]=k1 (layer1 dropout), [cid*4+2,3]=k2 (layer2 dropout)
//  [16+r*4+0,1]=randint k1, [16+r*4+2,3]=randint k2
__global__ void keys_kernel(uint32_t* keys){
  if(threadIdx.x==0 && blockIdx.x==0){
    for(int cid=0;cid<4;++cid){
      uint32_t K0=0u,K1=(uint32_t)cid;
      tf2x32(0u,42u,K0,K1);
      uint32_t a0=0u,a1=0u; tf2x32(K0,K1,a0,a1);
      uint32_t b0=0u,b1=1u; tf2x32(K0,K1,b0,b1);
      keys[cid*4+0]=a0; keys[cid*4+1]=a1;
      keys[cid*4+2]=b0; keys[cid*4+3]=b1;
    }
    for(int r=0;r<2;++r){
      uint32_t F0=0u,F1=(uint32_t)(2*r);
      tf2x32(0u,7u,F0,F1);
      uint32_t a0=0u,a1=0u; tf2x32(F0,F1,a0,a1);
      uint32_t b0=0u,b1=1u; tf2x32(F0,F1,b0,b1);
      keys[16+r*4+0]=a0; keys[16+r*4+1]=a1;
      keys[16+r*4+2]=b0; keys[16+r*4+3]=b1;
    }
  }
}

__global__ void count_kernel(const int* dst, int* cnt){
  int e = blockIdx.x*256 + threadIdx.x;
  if(e < NE) atomicAdd(&cnt[dst[e]], 1);
}

__global__ void scan_kernel(const int* cnt, int* off, int* cur, float* inv){
  __shared__ int part[1024];
  int t = threadIdx.x;
  const int CH = (NND + 1023)/1024;
  int lo = t*CH, hi = lo+CH; if(hi>NND) hi=NND;
  int s=0;
  for(int i=lo;i<hi;++i) s += cnt[i];
  part[t]=s;
  __syncthreads();
  if(t==0){ int run=0; for(int i=0;i<1024;++i){ int v=part[i]; part[i]=run; run+=v; } }
  __syncthreads();
  int run = part[t];
  for(int i=lo;i<hi;++i){
    off[i]=run; cur[i]=run;
    int c=cnt[i];
    inv[i]=1.0f/(float)(c>0?c:1);
    run+=c;
  }
  if(t==0) off[NND]=NE;
}

__global__ void fill_kernel(const int* dst, int* cur, int* col){
  int e = blockIdx.x*256 + threadIdx.x;
  if(e < NE){
    int d = dst[e];
    int slot = atomicAdd(&cur[d],1);
    col[slot] = e;
  }
}

// wave odd-even transposition sort of each CSR segment (deg<=64 in registers; rare fallback)
__global__ void __launch_bounds__(256) sortseg_wave_kernel(const int* off, int* col){
  int t=threadIdx.x, lane=t&63, w=t>>6;
  int node = blockIdx.x*4 + w;
  if(node>=NND) return;
  int lo=off[node], hi=off[node+1];
  int deg=hi-lo;
  if(deg<=1) return;
  if(deg<=64){
    int v = (lane<deg)? col[lo+lane] : 0x7fffffff;
    for(int p=0;p<64;++p){
      int partner;
      if((p&1)==0) partner = lane^1;
      else partner = (lane==0||lane==63)? lane : ((lane&1)? lane+1 : lane-1);
      int pv = __shfl(v, partner, 64);
      if(partner>lane) v = v<pv? v:pv;
      else if(partner<lane) v = v>pv? v:pv;
    }
    if(lane<deg) col[lo+lane]=v;
  } else if(lane==0){
    for(int i=lo+1;i<hi;++i){
      int v=col[i]; int j=i-1;
      while(j>=lo && col[j]>v){ col[j+1]=col[j]; --j; }
      col[j+1]=v;
    }
  }
}

// order-preserving batched gather (identical FP order to a plain sequential loop)
__device__ __forceinline__ float gather_seq(const float* __restrict__ src, int S, int d,
    const int* __restrict__ col, int lo, int hi, int lane){
  float acc=0.f;
  int deg=hi-lo, base=0;
  while(base<deg){
    int rem=deg-base; int cw = rem<64?rem:64;
    int cv = col[lo+base+ (lane<cw?lane:cw-1)];
    for(int k=0;k<cw;k+=8){
      int m=cw-k;
      float v0,v1,v2,v3,v4,v5,v6,v7;
      { int q=k;                 int s=__shfl(cv,q,64)>>5; v0=src[(size_t)s*S+d]; }
      { int q=(1<m)?k+1:k;       int s=__shfl(cv,q,64)>>5; v1=src[(size_t)s*S+d]; }
      { int q=(2<m)?k+2:k;       int s=__shfl(cv,q,64)>>5; v2=src[(size_t)s*S+d]; }
      { int q=(3<m)?k+3:k;       int s=__shfl(cv,q,64)>>5; v3=src[(size_t)s*S+d]; }
      { int q=(4<m)?k+4:k;       int s=__shfl(cv,q,64)>>5; v4=src[(size_t)s*S+d]; }
      { int q=(5<m)?k+5:k;       int s=__shfl(cv,q,64)>>5; v5=src[(size_t)s*S+d]; }
      { int q=(6<m)?k+6:k;       int s=__shfl(cv,q,64)>>5; v6=src[(size_t)s*S+d]; }
      { int q=(7<m)?k+7:k;       int s=__shfl(cv,q,64)>>5; v7=src[(size_t)s*S+d]; }
      acc+=v0;
      if(m>1)acc+=v1; if(m>2)acc+=v2; if(m>3)acc+=v3;
      if(m>4)acc+=v4; if(m>5)acc+=v5; if(m>6)acc+=v6; if(m>7)acc+=v7;
    }
    base+=cw;
  }
  return acc;
}

// h1base = leaky_relu(agg@Wl1.T + bl1 + x@Wr1.T)  (dropout applied separately)
__global__ void __launch_bounds__(256) sage1base_kernel(const float* __restrict__ x,
    const int* __restrict__ off, const int* __restrict__ col,
    const float* __restrict__ inv, const float* __restrict__ Wl,
    const float* __restrict__ bl, const float* __restrict__ Wr,
    float* __restrict__ h1base){
  __shared__ float sWlT[DD0*HH], sWrT[DD0*HH];
  __shared__ float sA[4][DD0], sX[4][DD0];
  int t=threadIdx.x, lane=t&63, w=t>>6;
  for(int j=t;j<HH*DD0;j+=256){
    int k=j>>5, h=j&31;
    sWlT[j]=Wl[h*DD0+k]; sWrT[j]=Wr[h*DD0+k];
  }
  int node=blockIdx.x*4+w;
  int lo=off[node], hi=off[node+1];
  float acc=gather_seq(x,DD0,lane,col,lo,hi,lane);
  acc *= inv[node];
  sA[w][lane]=acc;
  sX[w][lane]=x[(size_t)node*DD0+lane];
  __syncthreads();
  if(lane<HH){
    float s1=0.f, s2=0.f;
    for(int k=0;k<DD0;++k){
      s1 += sA[w][k]*sWlT[k*HH+lane];
      s2 += sX[w][k]*sWrT[k*HH+lane];
    }
    float v=s1+bl[lane]+s2;
    v = (v>=0.f) ? v : 0.01f*v;
    h1base[(size_t)node*HH+lane]=v;
  }
}

// h1 = dropout(h1base) for a given cid
__global__ void __launch_bounds__(256) mask_kernel(const float* __restrict__ h1base,
    const uint32_t* __restrict__ keys, int cid, float* __restrict__ h1){
  int j = blockIdx.x*256 + threadIdx.x;
  if(j < NND*HH){
    uint32_t bits = xorbits(keys[cid*4+0],keys[cid*4+1],(uint32_t)j);
    float v = h1base[j];
    h1[j] = ((bits>>31)==0u) ? 2.f*v : 0.f;
  }
}

// old full sage1 (fallback tiers)
__global__ void __launch_bounds__(256) sage1_kernel(const float* __restrict__ x,
    const int* __restrict__ off, const int* __restrict__ col,
    const float* __restrict__ inv, const float* __restrict__ Wl,
    const float* __restrict__ bl, const float* __restrict__ Wr,
    const uint32_t* __restrict__ keys, int cid, float* __restrict__ h1o){
  __shared__ float sWlT[DD0*HH], sWrT[DD0*HH];
  __shared__ float sA[4][DD0], sX[4][DD0];
  int t=threadIdx.x, lane=t&63, w=t>>6;
  for(int j=t;j<HH*DD0;j+=256){
    int k=j>>5, h=j&31;
    sWlT[j]=Wl[h*DD0+k]; sWrT[j]=Wr[h*DD0+k];
  }
  int node=blockIdx.x*4+w;
  int lo=off[node], hi=off[node+1];
  float acc=gather_seq(x,DD0,lane,col,lo,hi,lane);
  acc *= inv[node];
  sA[w][lane]=acc;
  sX[w][lane]=x[(size_t)node*DD0+lane];
  __syncthreads();
  if(lane<HH){
    float s1=0.f, s2=0.f;
    for(int k=0;k<DD0;++k){
      s1 += sA[w][k]*sWlT[k*HH+lane];
      s2 += sX[w][k]*sWrT[k*HH+lane];
    }
    float v=s1+bl[lane]+s2;
    v = (v>=0.f) ? v : 0.01f*v;
    uint32_t j=(uint32_t)(node*HH+lane);
    uint32_t bits = xorbits(keys[cid*4+0],keys[cid*4+1],j);
    v = ((bits>>31)==0u) ? 2.f*v : 0.f;
    h1o[(size_t)node*HH+lane]=v;
  }
}

// one normalized g-row for node n, full wave; sW*T[k*64+d] = W*2[d][k]
__device__ __forceinline__ float g_row_core(int n, int lane,
    const float* __restrict__ h1, const int* __restrict__ off,
    const int* __restrict__ col, const float* __restrict__ inv,
    const float* __restrict__ sWlT, const float* __restrict__ sWrT,
    const float* __restrict__ bl2, uint32_t k2a, uint32_t k2b){
  int lo=off[n], hi=off[n+1];
  int d=lane&31;
  float acc=gather_seq(h1,HH,d,col,lo,hi,lane);
  float aggd = acc*inv[n];
  float hd   = h1[(size_t)n*HH+d];
  float s1=0.f, s2=0.f;
  for(int k=0;k<HH;++k){
    float ak=__shfl(aggd,k,64);
    float hk=__shfl(hd,k,64);
    s1 += ak*sWlT[k*DD2+lane];
    s2 += hk*sWrT[k*DD2+lane];
  }
  float v=s1+bl2[lane]+s2;
  uint32_t j=(uint32_t)n*64u+(uint32_t)lane;
  uint32_t bits = xorbits(k2a,k2b,j);
  v = ((bits>>31)==0u) ? 2.f*v : 0.f;
  float ss=v*v;
  for(int m=1;m<64;m<<=1) ss += __shfl_xor(ss,m,64);
  return v/fmaxf(sqrtf(ss),1e-12f);
}

// one wave per g-row; grid = BB*NROWS/4
__global__ void __launch_bounds__(256) grows_kernel(
    const float* __restrict__ h1, const int* __restrict__ off,
    const int* __restrict__ col, const float* __restrict__ inv,
    const float* __restrict__ Wl2, const float* __restrict__ bl2,
    const float* __restrict__ Wr2, const uint32_t* __restrict__ keys, int cid,
    const int* __restrict__ users, const int* __restrict__ pid_arr,
    const int* __restrict__ adj, float* __restrict__ rowbuf){
  __shared__ float sWlT[HH*DD2], sWrT[HH*DD2];
  int t=threadIdx.x, lane=t&63, w=t>>6;
  for(int j=t;j<HH*DD2;j+=256){
    int k=j>>6, d=j&63;
    sWlT[j]=Wl2[d*HH+k]; sWrT[j]=Wr2[d*HH+k];
  }
  __syncthreads();
  int wg = blockIdx.x*4 + w;
  int b = wg/NROWS, r = wg - b*NROWS;
  int pid = pid_arr[b];
  int node = (r==0)? users[b] : ((r==1)? pid : adj[(size_t)pid*KN + (r-2)]);
  uint32_t k2a=keys[cid*4+2], k2b=keys[cid*4+3];
  float v = g_row_core(node,lane,h1,off,col,inv,sWlT,sWrT,bl2,k2a,k2b);
  rowbuf[(size_t)wg*DD2 + lane] = v;
}

__global__ void __launch_bounds__(64) sel1_kernel(
    const float* __restrict__ rowbuf,
    const int* __restrict__ users, const int* __restrict__ pid_arr,
    const int* __restrict__ adj, int* __restrict__ oh_out, float* __restrict__ l1_out){
  int b=blockIdx.x, t=threadIdx.x;
  __shared__ float wsh[DD2];
  __shared__ float ps[KN];
  const float* rb = rowbuf + (size_t)b*NROWS*DD2;
  wsh[t] = rb[t]*rb[DD2+t];
  __syncthreads();
  if(t<KN){
    float p=0.f;
    const float* rr = rb + (size_t)(2+t)*DD2;
    for(int d=0;d<DD2;++d) p += rr[d]*wsh[d];
    ps[t]=p;
  }
  __syncthreads();
  if(t==0){
    float m=ps[0]; for(int k=1;k<KN;++k) m=fmaxf(m,ps[k]);
    float s=0.f;  for(int k=0;k<KN;++k) s += expf(ps[k]-m);
    int best=0; float bv=ps[0];
    for(int k=1;k<KN;++k) if(ps[k]>bv){bv=ps[k];best=k;}
    oh_out[b]=adj[(size_t)pid_arr[b]*KN+best];
    l1_out[b]=(ps[best]-m)-logf(s);
  }
}

__global__ void __launch_bounds__(64) sel2_kernel(
    const float* __restrict__ rowbuf, const uint32_t* __restrict__ keys, int kf_idx,
    const int* __restrict__ users, const int* __restrict__ oh,
    const int* __restrict__ adj,
    const float* __restrict__ du, const float* __restrict__ di,
    const int* __restrict__ train, const int* __restrict__ neg,
    const float* __restrict__ l1, int round,
    int* __restrict__ gneg_out, float* __restrict__ out){
  int b=blockIdx.x, t=threadIdx.x;
  __shared__ float wsh[DD2];
  __shared__ float ps[KN], lps[KN], rk[KN];
  __shared__ int nid[KN], cand[KN];
  __shared__ float msh[2];
  const float* rb = rowbuf + (size_t)b*NROWS*DD2;
  wsh[t] = rb[t]*rb[DD2+t];
  __syncthreads();
  if(t<KN){
    float p=0.f;
    const float* rr = rb + (size_t)(2+t)*DD2;
    for(int d=0;d<DD2;++d) p += rr[d]*wsh[d];
    ps[t]=p;
  }
  __syncthreads();
  if(t==0){
    float m=ps[0]; for(int k=1;k<KN;++k) m=fmaxf(m,ps[k]);
    float s=0.f;  for(int k=0;k<KN;++k) s += expf(ps[k]-m);
    msh[0]=m; msh[1]=logf(s);
    for(int k=0;k<KN;++k) nid[k]=k;
    for(int i=1;i<KN;++i){
      int v=nid[i]; float pv=ps[v]; int j=i-1;
      while(j>=0 && ps[nid[j]]>pv){ nid[j+1]=nid[j]; --j; }
      nid[j+1]=v;
    }
  }
  __syncthreads();
  if(t<KN){
    int n=t, c=adj[(size_t)oh[b]*KN + nid[n]];
    if(c<0 || c>49999){
      uint32_t i0=(uint32_t)(b*KN+n);
      const uint32_t* fk = keys + 16 + kf_idx*4;
      uint32_t hb = xorbits(fk[0], fk[1], i0);
      uint32_t lb = xorbits(fk[2], fk[3], i0);
      c=(int)(((hb%50000u)*17296u + (lb%50000u))%50000u);
    }
    cand[n]=c;
    lps[n]=(ps[nid[n]]-msh[0])-msh[1];
    int u=users[b];
    float rr=0.f;
    for(int d=0;d<DD2;++d) rr += du[(size_t)u*DD2+d]*di[(size_t)c*DD2+d];
    rk[n]=rr;
  }
  __syncthreads();
  if(t==0){
    int best=0; float bv=rk[0];
    for(int n=1;n<KN;++n) if(rk[n]>bv){bv=rk[n];best=n;}
    int gn=cand[best]; float lsel=lps[best];
    bool it=false;
    for(int t2=0;t2<TT;++t2) if(train[(size_t)b*TT+t2]==gn){it=true;break;}
    if(it) gn=neg[b];
    gneg_out[b]=gn;
    out[b*2+round]        = (float)gn;
    out[BB*2 + b*2+round] = l1[b]+lsel;
  }
}

// ===== fallback (R14) fused steps =====
__global__ void __launch_bounds__(256) fstep1_kernel(
    const float* __restrict__ h1, const int* __restrict__ off,
    const int* __restrict__ col, const float* __restrict__ inv,
    const float* __restrict__ Wl2, const float* __restrict__ bl2,
    const float* __restrict__ Wr2, const uint32_t* __restrict__ keys, int cid,
    const int* __restrict__ users, const int* __restrict__ pid_arr,
    const int* __restrict__ adj, int* __restrict__ oh_out, float* __restrict__ l1_out){
  __shared__ float sWlT[HH*DD2], sWrT[HH*DD2];
  __shared__ float rows[2+KN][DD2+1];
  __shared__ int nds[2+KN];
  __shared__ float ps[KN];
  int t=threadIdx.x, lane=t&63, w=t>>6, b=blockIdx.x;
  for(int j=t;j<HH*DD2;j+=256){
    int k=j>>6, d=j&63;
    sWlT[j]=Wl2[d*HH+k]; sWrT[j]=Wr2[d*HH+k];
  }
  if(t==0){ nds[0]=users[b]; nds[1]=pid_arr[b]; }
  if(t>=2 && t<2+KN) nds[t]=adj[(size_t)pid_arr[b]*KN + (t-2)];
  __syncthreads();
  uint32_t k2a=keys[cid*4+2], k2b=keys[cid*4+3];
  for(int r=w; r<2+KN; r+=4)
    rows[r][lane]=g_row_core(nds[r],lane,h1,off,col,inv,sWlT,sWrT,bl2,k2a,k2b);
  __syncthreads();
  if(t<KN){
    float p=0.f;
    for(int d=0;d<DD2;++d) p += rows[2+t][d]*(rows[0][d]*rows[1][d]);
    ps[t]=p;
  }
  __syncthreads();
  if(t==0){
    float m=ps[0]; for(int k=1;k<KN;++k) m=fmaxf(m,ps[k]);
    float s=0.f;  for(int k=0;k<KN;++k) s += expf(ps[k]-m);
    int best=0; float bv=ps[0];
    for(int k=1;k<KN;++k) if(ps[k]>bv){bv=ps[k];best=k;}
    oh_out[b]=nds[2+best];
    l1_out[b]=(ps[best]-m)-logf(s);
  }
}

__global__ void __launch_bounds__(256) fstep2_kernel(
    const float* __restrict__ h1, const int* __restrict__ off,
    const int* __restrict__ col, const float* __restrict__ inv,
    const float* __restrict__ Wl2, const float* __restrict__ bl2,
    const float* __restrict__ Wr2, const uint32_t* __restrict__ keys,
    int cid, int kf_idx,
    const int* __restrict__ users, const int* __restrict__ oh,
    const int* __restrict__ adj,
    const float* __restrict__ du, const float* __restrict__ di,
    const int* __restrict__ train, const int* __restrict__ neg,
    const float* __restrict__ l1, int round,
    int* __restrict__ gneg_out, float* __restrict__ out){
  __shared__ float sWlT[HH*DD2], sWrT[HH*DD2];
  __shared__ float rows[2+KN][DD2+1];
  __shared__ int nds[2+KN];
  __shared__ float ps[KN], lps[KN], rk[KN];
  __shared__ int nid[KN], cand[KN];
  __shared__ float msh[2];
  int t=threadIdx.x, lane=t&63, w=t>>6, b=blockIdx.x;
  for(int j=t;j<HH*DD2;j+=256){
    int k=j>>6, d=j&63;
    sWlT[j]=Wl2[d*HH+k]; sWrT[j]=Wr2[d*HH+k];
  }
  if(t==0){ nds[0]=users[b]; nds[1]=oh[b]; }
  if(t>=2 && t<2+KN) nds[t]=adj[(size_t)oh[b]*KN + (t-2)];
  __syncthreads();
  uint32_t k2a=keys[cid*4+2], k2b=keys[cid*4+3];
  for(int r=w; r<2+KN; r+=4)
    rows[r][lane]=g_row_core(nds[r],lane,h1,off,col,inv,sWlT,sWrT,bl2,k2a,k2b);
  __syncthreads();
  if(t<KN){
    float p=0.f;
    for(int d=0;d<DD2;++d) p += rows[2+t][d]*(rows[0][d]*rows[1][d]);
    ps[t]=p;
  }
  __syncthreads();
  if(t==0){
    float m=ps[0]; for(int k=1;k<KN;++k) m=fmaxf(m,ps[k]);
    float s=0.f;  for(int k=0;k<KN;++k) s += expf(ps[k]-m);
    msh[0]=m; msh[1]=logf(s);
    for(int k=0;k<KN;++k) nid[k]=k;
    for(int i=1;i<KN;++i){
      int v=nid[i]; float pv=ps[v]; int j=i-1;
      while(j>=0 && ps[nid[j]]>pv){ nid[j+1]=nid[j]; --j; }
      nid[j+1]=v;
    }
  }
  __syncthreads();
  if(t<KN){
    int n=t, c=nds[2+nid[n]];
    if(c<0 || c>49999){
      uint32_t i0=(uint32_t)(b*KN+n);
      const uint32_t* fk = keys + 16 + kf_idx*4;
      uint32_t hb = xorbits(fk[0], fk[1], i0);
      uint32_t lb = xorbits(fk[2], fk[3], i0);
      c=(int)(((hb%50000u)*17296u + (lb%50000u))%50000u);
    }
    cand[n]=c;
    lps[n]=(ps[nid[n]]-msh[0])-msh[1];
    int u=nds[0];
    float rr=0.f;
    for(int d=0;d<DD2;++d) rr += du[(size_t)u*DD2+d]*di[(size_t)c*DD2+d];
    rk[n]=rr;
  }
  __syncthreads();
  if(t==0){
    int best=0; float bv=rk[0];
    for(int n=1;n<KN;++n) if(rk[n]>bv){bv=rk[n];best=n;}
    int gn=cand[best]; float lsel=lps[best];
    bool it=false;
    for(int t2=0;t2<TT;++t2) if(train[(size_t)b*TT+t2]==gn){it=true;break;}
    if(it) gn=neg[b];
    gneg_out[b]=gn;
    out[b*2+round]        = (float)gn;
    out[BB*2 + b*2+round] = l1[b]+lsel;
  }
}

extern "C" void kernel_launch(void* const* d_in, const int* in_sizes, int n_in,
                              void* d_out, int out_size, void* d_ws, size_t ws_size,
                              hipStream_t stream) {
  const int*   users=(const int*)d_in[0];
  const int*   pos  =(const int*)d_in[1];
  const int*   neg  =(const int*)d_in[2];
  const int*   train=(const int*)d_in[3];
  const int*   adj  =(const int*)d_in[4];
  const int*   edge =(const int*)d_in[5];
  const float* ent  =(const float*)d_in[6];
  const float* Wl1  =(const float*)d_in[7];
  const float* bl1  =(const float*)d_in[8];
  const float* Wr1  =(const float*)d_in[9];
  const float* Wl2  =(const float*)d_in[10];
  const float* bl2  =(const float*)d_in[11];
  const float* Wr2  =(const float*)d_in[12];
  const float* du   =(const float*)d_in[13];
  const float* di   =(const float*)d_in[14];
  float* out=(float*)d_out;

  char* wsb=(char*)d_ws;
  size_t o=0;
  auto alloc=[&](size_t n)->char*{ char* p=wsb+o; o=(o+n+255)&~(size_t)255; return p; };
  uint32_t* keys=(uint32_t*)alloc(32*4);
  int*   ohb=(int*)alloc((size_t)BB*4);
  float* l1b=(float*)alloc((size_t)BB*4);
  int*   g1b=(int*)alloc((size_t)BB*4);
  int*   g2b=(int*)alloc((size_t)BB*4);
  int*   cnt=(int*)alloc((size_t)NND*4);
  int*   off=(int*)alloc((size_t)(NND+1)*4);
  int*   cur=(int*)alloc((size_t)NND*4);
  float* inv=(float*)alloc((size_t)NND*4);
  int*   col=(int*)alloc((size_t)NE*4);
  float* h1 =(float*)alloc((size_t)NND*HH*4);
  float* rowbuf=(float*)alloc((size_t)BB*NROWS*DD2*4);
  size_t o_rowbuf = o;
  float* h1base=(float*)alloc((size_t)NND*HH*4);
  int tier = (ws_size >= o) ? 2 : ((ws_size >= o_rowbuf) ? 1 : 0);

  hipMemsetAsync(cnt,0,(size_t)NND*4,stream);
  keys_kernel<<<1,64,0,stream>>>(keys);

  count_kernel<<<NE/256,256,0,stream>>>(edge,cnt);
  scan_kernel<<<1,1024,0,stream>>>(cnt,off,cur,inv);
  fill_kernel<<<NE/256,256,0,stream>>>(edge,cur,col);
  sortseg_wave_kernel<<<NND/4,256,0,stream>>>(off,col);

  const int GROWS_GRID = BB*NROWS/4;   // 17408
  const int MASK_GRID  = (NND*HH+255)/256;

  if(tier==2){
    sage1base_kernel<<<NND/4,256,0,stream>>>(ent,off,col,inv,Wl1,bl1,Wr1,h1base);
    for(int r=0;r<2;++r){
      const int* pid = (r==0)? pos : g1b;
      int cidA=2*r, cidB=2*r+1;
      mask_kernel<<<MASK_GRID,256,0,stream>>>(h1base,keys,cidA,h1);
      grows_kernel<<<GROWS_GRID,256,0,stream>>>(h1,off,col,inv,Wl2,bl2,Wr2,keys,cidA,
                                                users,pid,adj,rowbuf);
      sel1_kernel<<<BB,64,0,stream>>>(rowbuf,users,pid,adj,ohb,l1b);
      mask_kernel<<<MASK_GRID,256,0,stream>>>(h1base,keys,cidB,h1);
      grows_kernel<<<GROWS_GRID,256,0,stream>>>(h1,off,col,inv,Wl2,bl2,Wr2,keys,cidB,
                                                users,ohb,adj,rowbuf);
      sel2_kernel<<<BB,64,0,stream>>>(rowbuf,keys,r,users,ohb,adj,du,di,train,neg,l1b,r,
                                      (r==0)?g1b:g2b,out);
    }
  } else if(tier==1){
    for(int r=0;r<2;++r){
      const int* pid = (r==0)? pos : g1b;
      int cidA=2*r, cidB=2*r+1;
      sage1_kernel<<<NND/4,256,0,stream>>>(ent,off,col,inv,Wl1,bl1,Wr1,keys,cidA,h1);
      grows_kernel<<<GROWS_GRID,256,0,stream>>>(h1,off,col,inv,Wl2,bl2,Wr2,keys,cidA,
                                                users,pid,adj,rowbuf);
      sel1_kernel<<<BB,64,0,stream>>>(rowbuf,users,pid,adj,ohb,l1b);
      sage1_kernel<<<NND/4,256,0,stream>>>(ent,off,col,inv,Wl1,bl1,Wr1,keys,cidB,h1);
      grows_kernel<<<GROWS_GRID,256,0,stream>>>(h1,off,col,inv,Wl2,bl2,Wr2,keys,cidB,
                                                users,ohb,adj,rowbuf);
      sel2_kernel<<<BB,64,0,stream>>>(rowbuf,keys,r,users,ohb,adj,du,di,train,neg,l1b,r,
                                      (r==0)?g1b:g2b,out);
    }
  } else {
    for(int r=0;r<2;++r){
      const int* pid = (r==0)? pos : g1b;
      int cidA=2*r, cidB=2*r+1;
      sage1_kernel<<<NND/4,256,0,stream>>>(ent,off,col,inv,Wl1,bl1,Wr1,keys,cidA,h1);
      fstep1_kernel<<<BB,256,0,stream>>>(h1,off,col,inv,Wl2,bl2,Wr2,keys,cidA,
                                         users,pid,adj,ohb,l1b);
      sage1_kernel<<<NND/4,256,0,stream>>>(ent,off,col,inv,Wl1,bl1,Wr1,keys,cidB,h1);
      fstep2_kernel<<<BB,256,0,stream>>>(h1,off,col,inv,Wl2,bl2,Wr2,keys,cidB,r,
                                         users,ohb,adj,du,di,train,neg,l1b,r,
                                         (r==0)?g1b:g2b,out);
    }
  }
}

// Round 17
// 1329.811 us; speedup vs baseline: 2.7683x; 1.4392x over previous
//
#include <hip/hip_runtime.h>
#include <hip/hip_bf16.h>
#include <stdint.h>

#define NND 100000
#define KN 32
#define NE (NND*KN)
#define BB 2048
#define TT 50
#define DD0 64
#define HH 32
#define DD2 64
#define NROWS 34
#define BSH 9
#define NBUK ((NND + (1<<BSH) - 1) >> BSH)   // 196
#define PCHUNK 6250                           // NE / 512

typedef unsigned long long ull;

__device__ __forceinline__ void tf2x32(uint32_t k0, uint32_t k1, uint32_t& x0, uint32_t& x1){
  uint32_t k2 = k0 ^ k1 ^ 0x1BD11BDAu;
#define TFR(r) { x0 += x1; x1 = (x1<<(r)) | (x1>>(32-(r))); x1 ^= x0; }
  x0 += k0; x1 += k1;
  TFR(13) TFR(15) TFR(26) TFR(6)
  x0 += k1; x1 += k2 + 1u;
  TFR(17) TFR(29) TFR(16) TFR(24)
  x0 += k2; x1 += k0 + 2u;
  TFR(13) TFR(15) TFR(26) TFR(6)
  x0 += k0; x1 += k1 + 3u;
  TFR(17) TFR(29) TFR(16) TFR(24)
  x0 += k1; x1 += k2 + 4u;
  TFR(13) TFR(15) TFR(26) TFR(6)
  x0 += k2; x1 += k0 + 5u;
#undef TFR
}

__device__ __forceinline__ uint32_t xorbits(uint32_t ka, uint32_t kb, uint32_t i){
  uint32_t x0=0u, x1=i;
  tf2x32(ka,kb,x0,x1);
  return x0^x1;
}

__global__ void keys_kernel(uint32_t* keys){
  if(threadIdx.x==0 && blockIdx.x==0){
    for(int cid=0;cid<4;++cid){
      uint32_t K0=0u,K1=(uint32_t)cid;
      tf2x32(0u,42u,K0,K1);
      uint32_t a0=0u,a1=0u; tf2x32(K0,K1,a0,a1);
      uint32_t b0=0u,b1=1u; tf2x32(K0,K1,b0,b1);
      keys[cid*4+0]=a0; keys[cid*4+1]=a1;
      keys[cid*4+2]=b0; keys[cid*4+3]=b1;
    }
    for(int r=0;r<2;++r){
      uint32_t F0=0u,F1=(uint32_t)(2*r);
      tf2x32(0u,7u,F0,F1);
      uint32_t a0=0u,a1=0u; tf2x32(F0,F1,a0,a1);
      uint32_t b0=0u,b1=1u; tf2x32(F0,F1,b0,b1);
      keys[16+r*4+0]=a0; keys[16+r*4+1]=a1;
      keys[16+r*4+2]=b0; keys[16+r*4+3]=b1;
    }
  }
}

// ===== new CSR build: bucketed partition (write-amplification-free) =====
__global__ void __launch_bounds__(256) bcount_kernel(const int* __restrict__ edge, int* bcnt){
  __shared__ int h[NBUK];
  int t=threadIdx.x;
  for(int i=t;i<NBUK;i+=256) h[i]=0;
  __syncthreads();
  int start=blockIdx.x*PCHUNK, end=start+PCHUNK;
  for(int e=start+t;e<end;e+=256) atomicAdd(&h[edge[e]>>BSH],1);
  __syncthreads();
  for(int i=t;i<NBUK;i+=256) if(h[i]) atomicAdd(&bcnt[i],h[i]);
}

__global__ void bscan_kernel(const int* bcnt, int* boff, int* bcur, int* off){
  if(threadIdx.x==0 && blockIdx.x==0){
    int run=0;
    for(int i=0;i<NBUK;++i){ boff[i]=run; bcur[i]=run; run+=bcnt[i]; }
    boff[NBUK]=run;
    off[NND]=NE;
  }
}

__global__ void __launch_bounds__(256) bscatter_kernel(const int* __restrict__ edge,
    int* bcur, ull* __restrict__ tmp8){
  __shared__ int h[NBUK], base[NBUK], lcur[NBUK];
  int t=threadIdx.x;
  for(int i=t;i<NBUK;i+=256){ h[i]=0; lcur[i]=0; }
  __syncthreads();
  int start=blockIdx.x*PCHUNK, end=start+PCHUNK;
  for(int e=start+t;e<end;e+=256) atomicAdd(&h[edge[e]>>BSH],1);
  __syncthreads();
  for(int i=t;i<NBUK;i+=256) base[i] = h[i]? atomicAdd(&bcur[i],h[i]) : 0;
  __syncthreads();
  for(int e=start+t;e<end;e+=256){
    int d=edge[e];
    int b=d>>BSH;
    int r=atomicAdd(&lcur[b],1);
    tmp8[base[b]+r] = (((ull)(unsigned)d)<<32) | (unsigned)e;
  }
}

__global__ void __launch_bounds__(256) bucket_csr_kernel(const int* __restrict__ boff,
    const ull* __restrict__ tmp8, int* __restrict__ off, float* __restrict__ inv,
    int* __restrict__ col){
  __shared__ int cnt[512], pref[512], cur2[512];
  int b=blockIdx.x, t=threadIdx.x;
  int nb=b<<BSH;
  for(int i=t;i<512;i+=256) cnt[i]=0;
  __syncthreads();
  int lo=boff[b], hi=boff[b+1];
  for(int i=lo+t;i<hi;i+=256){
    int ld=(int)(tmp8[i]>>32)-nb;
    atomicAdd(&cnt[ld],1);
  }
  __syncthreads();
  if(t==0){ int run=lo; for(int i=0;i<512;++i){ pref[i]=run; cur2[i]=run; run+=cnt[i]; } }
  __syncthreads();
  for(int i=t;i<512;i+=256){
    int d=nb+i;
    if(d<NND){ off[d]=pref[i]; int c=cnt[i]; inv[d]=1.0f/(float)(c>0?c:1); }
  }
  __syncthreads();
  for(int i=lo+t;i<hi;i+=256){
    ull v=tmp8[i];
    int ld=(int)(v>>32)-nb;
    int r=atomicAdd(&cur2[ld],1);
    col[r]=(int)(v&0xffffffffu);
  }
}

// ===== old build (fallback tiers) =====
__global__ void count_kernel(const int* dst, int* cnt){
  int e = blockIdx.x*256 + threadIdx.x;
  if(e < NE) atomicAdd(&cnt[dst[e]], 1);
}
__global__ void scan_kernel(const int* cnt, int* off, int* cur, float* inv){
  __shared__ int part[1024];
  int t = threadIdx.x;
  const int CH = (NND + 1023)/1024;
  int lo = t*CH, hi = lo+CH; if(hi>NND) hi=NND;
  int s=0;
  for(int i=lo;i<hi;++i) s += cnt[i];
  part[t]=s;
  __syncthreads();
  if(t==0){ int run=0; for(int i=0;i<1024;++i){ int v=part[i]; part[i]=run; run+=v; } }
  __syncthreads();
  int run = part[t];
  for(int i=lo;i<hi;++i){
    off[i]=run; cur[i]=run;
    int c=cnt[i];
    inv[i]=1.0f/(float)(c>0?c:1);
    run+=c;
  }
  if(t==0) off[NND]=NE;
}
__global__ void fill_kernel(const int* dst, int* cur, int* col){
  int e = blockIdx.x*256 + threadIdx.x;
  if(e < NE){
    int d = dst[e];
    int slot = atomicAdd(&cur[d],1);
    col[slot] = e;
  }
}

// wave odd-even transposition sort of each CSR segment
__global__ void __launch_bounds__(256) sortseg_wave_kernel(const int* off, int* col){
  int t=threadIdx.x, lane=t&63, w=t>>6;
  int node = blockIdx.x*4 + w;
  if(node>=NND) return;
  int lo=off[node], hi=off[node+1];
  int deg=hi-lo;
  if(deg<=1) return;
  if(deg<=64){
    int v = (lane<deg)? col[lo+lane] : 0x7fffffff;
    for(int p=0;p<64;++p){
      int partner;
      if((p&1)==0) partner = lane^1;
      else partner = (lane==0||lane==63)? lane : ((lane&1)? lane+1 : lane-1);
      int pv = __shfl(v, partner, 64);
      if(partner>lane) v = v<pv? v:pv;
      else if(partner<lane) v = v>pv? v:pv;
    }
    if(lane<deg) col[lo+lane]=v;
  } else if(lane==0){
    for(int i=lo+1;i<hi;++i){
      int v=col[i]; int j=i-1;
      while(j>=lo && col[j]>v){ col[j+1]=col[j]; --j; }
      col[j+1]=v;
    }
  }
}

// order-preserving batched gather (identical FP order to a plain sequential loop)
__device__ __forceinline__ float gather_seq(const float* __restrict__ src, int S, int d,
    const int* __restrict__ col, int lo, int hi, int lane){
  float acc=0.f;
  int deg=hi-lo, base=0;
  while(base<deg){
    int rem=deg-base; int cw = rem<64?rem:64;
    int cv = col[lo+base+ (lane<cw?lane:cw-1)];
    for(int k=0;k<cw;k+=8){
      int m=cw-k;
      float v0,v1,v2,v3,v4,v5,v6,v7;
      { int q=k;                 int s=__shfl(cv,q,64)>>5; v0=src[(size_t)s*S+d]; }
      { int q=(1<m)?k+1:k;       int s=__shfl(cv,q,64)>>5; v1=src[(size_t)s*S+d]; }
      { int q=(2<m)?k+2:k;       int s=__shfl(cv,q,64)>>5; v2=src[(size_t)s*S+d]; }
      { int q=(3<m)?k+3:k;       int s=__shfl(cv,q,64)>>5; v3=src[(size_t)s*S+d]; }
      { int q=(4<m)?k+4:k;       int s=__shfl(cv,q,64)>>5; v4=src[(size_t)s*S+d]; }
      { int q=(5<m)?k+5:k;       int s=__shfl(cv,q,64)>>5; v5=src[(size_t)s*S+d]; }
      { int q=(6<m)?k+6:k;       int s=__shfl(cv,q,64)>>5; v6=src[(size_t)s*S+d]; }
      { int q=(7<m)?k+7:k;       int s=__shfl(cv,q,64)>>5; v7=src[(size_t)s*S+d]; }
      acc+=v0;
      if(m>1)acc+=v1; if(m>2)acc+=v2; if(m>3)acc+=v3;
      if(m>4)acc+=v4; if(m>5)acc+=v5; if(m>6)acc+=v6; if(m>7)acc+=v7;
    }
    base+=cw;
  }
  return acc;
}

// h1base = leaky_relu(agg@Wl1.T + bl1 + x@Wr1.T)
__global__ void __launch_bounds__(256) sage1base_kernel(const float* __restrict__ x,
    const int* __restrict__ off, const int* __restrict__ col,
    const float* __restrict__ inv, const float* __restrict__ Wl,
    const float* __restrict__ bl, const float* __restrict__ Wr,
    float* __restrict__ h1base){
  __shared__ float sWlT[DD0*HH], sWrT[DD0*HH];
  __shared__ float sA[4][DD0], sX[4][DD0];
  int t=threadIdx.x, lane=t&63, w=t>>6;
  for(int j=t;j<HH*DD0;j+=256){
    int k=j>>5, h=j&31;
    sWlT[j]=Wl[h*DD0+k]; sWrT[j]=Wr[h*DD0+k];
  }
  int node=blockIdx.x*4+w;
  int lo=off[node], hi=off[node+1];
  float acc=gather_seq(x,DD0,lane,col,lo,hi,lane);
  acc *= inv[node];
  sA[w][lane]=acc;
  sX[w][lane]=x[(size_t)node*DD0+lane];
  __syncthreads();
  if(lane<HH){
    float s1=0.f, s2=0.f;
    for(int k=0;k<DD0;++k){
      s1 += sA[w][k]*sWlT[k*HH+lane];
      s2 += sX[w][k]*sWrT[k*HH+lane];
    }
    float v=s1+bl[lane]+s2;
    v = (v>=0.f) ? v : 0.01f*v;
    h1base[(size_t)node*HH+lane]=v;
  }
}

__global__ void __launch_bounds__(256) mask_kernel(const float* __restrict__ h1base,
    const uint32_t* __restrict__ keys, int cid, float* __restrict__ h1){
  int j = blockIdx.x*256 + threadIdx.x;
  if(j < NND*HH){
    uint32_t bits = xorbits(keys[cid*4+0],keys[cid*4+1],(uint32_t)j);
    float v = h1base[j];
    h1[j] = ((bits>>31)==0u) ? 2.f*v : 0.f;
  }
}

// old full sage1 (fallback tiers)
__global__ void __launch_bounds__(256) sage1_kernel(const float* __restrict__ x,
    const int* __restrict__ off, const int* __restrict__ col,
    const float* __restrict__ inv, const float* __restrict__ Wl,
    const float* __restrict__ bl, const float* __restrict__ Wr,
    const uint32_t* __restrict__ keys, int cid, float* __restrict__ h1o){
  __shared__ float sWlT[DD0*HH], sWrT[DD0*HH];
  __shared__ float sA[4][DD0], sX[4][DD0];
  int t=threadIdx.x, lane=t&63, w=t>>6;
  for(int j=t;j<HH*DD0;j+=256){
    int k=j>>5, h=j&31;
    sWlT[j]=Wl[h*DD0+k]; sWrT[j]=Wr[h*DD0+k];
  }
  int node=blockIdx.x*4+w;
  int lo=off[node], hi=off[node+1];
  float acc=gather_seq(x,DD0,lane,col,lo,hi,lane);
  acc *= inv[node];
  sA[w][lane]=acc;
  sX[w][lane]=x[(size_t)node*DD0+lane];
  __syncthreads();
  if(lane<HH){
    float s1=0.f, s2=0.f;
    for(int k=0;k<DD0;++k){
      s1 += sA[w][k]*sWlT[k*HH+lane];
      s2 += sX[w][k]*sWrT[k*HH+lane];
    }
    float v=s1+bl[lane]+s2;
    v = (v>=0.f) ? v : 0.01f*v;
    uint32_t j=(uint32_t)(node*HH+lane);
    uint32_t bits = xorbits(keys[cid*4+0],keys[cid*4+1],j);
    v = ((bits>>31)==0u) ? 2.f*v : 0.f;
    h1o[(size_t)node*HH+lane]=v;
  }
}

__device__ __forceinline__ float g_row_core(int n, int lane,
    const float* __restrict__ h1, const int* __restrict__ off,
    const int* __restrict__ col, const float* __restrict__ inv,
    const float* __restrict__ sWlT, const float* __restrict__ sWrT,
    const float* __restrict__ bl2, uint32_t k2a, uint32_t k2b){
  int lo=off[n], hi=off[n+1];
  int d=lane&31;
  float acc=gather_seq(h1,HH,d,col,lo,hi,lane);
  float aggd = acc*inv[n];
  float hd   = h1[(size_t)n*HH+d];
  float s1=0.f, s2=0.f;
  for(int k=0;k<HH;++k){
    float ak=__shfl(aggd,k,64);
    float hk=__shfl(hd,k,64);
    s1 += ak*sWlT[k*DD2+lane];
    s2 += hk*sWrT[k*DD2+lane];
  }
  float v=s1+bl2[lane]+s2;
  uint32_t j=(uint32_t)n*64u+(uint32_t)lane;
  uint32_t bits = xorbits(k2a,k2b,j);
  v = ((bits>>31)==0u) ? 2.f*v : 0.f;
  float ss=v*v;
  for(int m=1;m<64;m<<=1) ss += __shfl_xor(ss,m,64);
  return v/fmaxf(sqrtf(ss),1e-12f);
}

__global__ void __launch_bounds__(256) grows_kernel(
    const float* __restrict__ h1, const int* __restrict__ off,
    const int* __restrict__ col, const float* __restrict__ inv,
    const float* __restrict__ Wl2, const float* __restrict__ bl2,
    const float* __restrict__ Wr2, const uint32_t* __restrict__ keys, int cid,
    const int* __restrict__ users, const int* __restrict__ pid_arr,
    const int* __restrict__ adj, float* __restrict__ rowbuf){
  __shared__ float sWlT[HH*DD2], sWrT[HH*DD2];
  int t=threadIdx.x, lane=t&63, w=t>>6;
  for(int j=t;j<HH*DD2;j+=256){
    int k=j>>6, d=j&63;
    sWlT[j]=Wl2[d*HH+k]; sWrT[j]=Wr2[d*HH+k];
  }
  __syncthreads();
  int wg = blockIdx.x*4 + w;
  int b = wg/NROWS, r = wg - b*NROWS;
  int pid = pid_arr[b];
  int node = (r==0)? users[b] : ((r==1)? pid : adj[(size_t)pid*KN + (r-2)]);
  uint32_t k2a=keys[cid*4+2], k2b=keys[cid*4+3];
  float v = g_row_core(node,lane,h1,off,col,inv,sWlT,sWrT,bl2,k2a,k2b);
  rowbuf[(size_t)wg*DD2 + lane] = v;
}

__global__ void __launch_bounds__(64) sel1_kernel(
    const float* __restrict__ rowbuf,
    const int* __restrict__ users, const int* __restrict__ pid_arr,
    const int* __restrict__ adj, int* __restrict__ oh_out, float* __restrict__ l1_out){
  int b=blockIdx.x, t=threadIdx.x;
  __shared__ float wsh[DD2];
  __shared__ float ps[KN];
  const float* rb = rowbuf + (size_t)b*NROWS*DD2;
  wsh[t] = rb[t]*rb[DD2+t];
  __syncthreads();
  if(t<KN){
    float p=0.f;
    const float* rr = rb + (size_t)(2+t)*DD2;
    for(int d=0;d<DD2;++d) p += rr[d]*wsh[d];
    ps[t]=p;
  }
  __syncthreads();
  if(t==0){
    float m=ps[0]; for(int k=1;k<KN;++k) m=fmaxf(m,ps[k]);
    float s=0.f;  for(int k=0;k<KN;++k) s += expf(ps[k]-m);
    int best=0; float bv=ps[0];
    for(int k=1;k<KN;++k) if(ps[k]>bv){bv=ps[k];best=k;}
    oh_out[b]=adj[(size_t)pid_arr[b]*KN+best];
    l1_out[b]=(ps[best]-m)-logf(s);
  }
}

__global__ void __launch_bounds__(64) sel2_kernel(
    const float* __restrict__ rowbuf, const uint32_t* __restrict__ keys, int kf_idx,
    const int* __restrict__ users, const int* __restrict__ oh,
    const int* __restrict__ adj,
    const float* __restrict__ du, const float* __restrict__ di,
    const int* __restrict__ train, const int* __restrict__ neg,
    const float* __restrict__ l1, int round,
    int* __restrict__ gneg_out, float* __restrict__ out){
  int b=blockIdx.x, t=threadIdx.x;
  __shared__ float wsh[DD2];
  __shared__ float ps[KN], lps[KN], rk[KN];
  __shared__ int nid[KN], cand[KN];
  __shared__ float msh[2];
  const float* rb = rowbuf + (size_t)b*NROWS*DD2;
  wsh[t] = rb[t]*rb[DD2+t];
  __syncthreads();
  if(t<KN){
    float p=0.f;
    const float* rr = rb + (size_t)(2+t)*DD2;
    for(int d=0;d<DD2;++d) p += rr[d]*wsh[d];
    ps[t]=p;
  }
  __syncthreads();
  if(t==0){
    float m=ps[0]; for(int k=1;k<KN;++k) m=fmaxf(m,ps[k]);
    float s=0.f;  for(int k=0;k<KN;++k) s += expf(ps[k]-m);
    msh[0]=m; msh[1]=logf(s);
    for(int k=0;k<KN;++k) nid[k]=k;
    for(int i=1;i<KN;++i){
      int v=nid[i]; float pv=ps[v]; int j=i-1;
      while(j>=0 && ps[nid[j]]>pv){ nid[j+1]=nid[j]; --j; }
      nid[j+1]=v;
    }
  }
  __syncthreads();
  if(t<KN){
    int n=t, c=adj[(size_t)oh[b]*KN + nid[n]];
    if(c<0 || c>49999){
      uint32_t i0=(uint32_t)(b*KN+n);
      const uint32_t* fk = keys + 16 + kf_idx*4;
      uint32_t hb = xorbits(fk[0], fk[1], i0);
      uint32_t lb = xorbits(fk[2], fk[3], i0);
      c=(int)(((hb%50000u)*17296u + (lb%50000u))%50000u);
    }
    cand[n]=c;
    lps[n]=(ps[nid[n]]-msh[0])-msh[1];
    int u=users[b];
    float rr=0.f;
    for(int d=0;d<DD2;++d) rr += du[(size_t)u*DD2+d]*di[(size_t)c*DD2+d];
    rk[n]=rr;
  }
  __syncthreads();
  if(t==0){
    int best=0; float bv=rk[0];
    for(int n=1;n<KN;++n) if(rk[n]>bv){bv=rk[n];best=n;}
    int gn=cand[best]; float lsel=lps[best];
    bool it=false;
    for(int t2=0;t2<TT;++t2) if(train[(size_t)b*TT+t2]==gn){it=true;break;}
    if(it) gn=neg[b];
    gneg_out[b]=gn;
    out[b*2+round]        = (float)gn;
    out[BB*2 + b*2+round] = l1[b]+lsel;
  }
}

// ===== fallback (R14) fused steps =====
__global__ void __launch_bounds__(256) fstep1_kernel(
    const float* __restrict__ h1, const int* __restrict__ off,
    const int* __restrict__ col, const float* __restrict__ inv,
    const float* __restrict__ Wl2, const float* __restrict__ bl2,
    const float* __restrict__ Wr2, const uint32_t* __restrict__ keys, int cid,
    const int* __restrict__ users, const int* __restrict__ pid_arr,
    const int* __restrict__ adj, int* __restrict__ oh_out, float* __restrict__ l1_out){
  __shared__ float sWlT[HH*DD2], sWrT[HH*DD2];
  __shared__ float rows[2+KN][DD2+1];
  __shared__ int nds[2+KN];
  __shared__ float ps[KN];
  int t=threadIdx.x, lane=t&63, w=t>>6, b=blockIdx.x;
  for(int j=t;j<HH*DD2;j+=256){
    int k=j>>6, d=j&63;
    sWlT[j]=Wl2[d*HH+k]; sWrT[j]=Wr2[d*HH+k];
  }
  if(t==0){ nds[0]=users[b]; nds[1]=pid_arr[b]; }
  if(t>=2 && t<2+KN) nds[t]=adj[(size_t)pid_arr[b]*KN + (t-2)];
  __syncthreads();
  uint32_t k2a=keys[cid*4+2], k2b=keys[cid*4+3];
  for(int r=w; r<2+KN; r+=4)
    rows[r][lane]=g_row_core(nds[r],lane,h1,off,col,inv,sWlT,sWrT,bl2,k2a,k2b);
  __syncthreads();
  if(t<KN){
    float p=0.f;
    for(int d=0;d<DD2;++d) p += rows[2+t][d]*(rows[0][d]*rows[1][d]);
    ps[t]=p;
  }
  __syncthreads();
  if(t==0){
    float m=ps[0]; for(int k=1;k<KN;++k) m=fmaxf(m,ps[k]);
    float s=0.f;  for(int k=0;k<KN;++k) s += expf(ps[k]-m);
    int best=0; float bv=ps[0];
    for(int k=1;k<KN;++k) if(ps[k]>bv){bv=ps[k];best=k;}
    oh_out[b]=nds[2+best];
    l1_out[b]=(ps[best]-m)-logf(s);
  }
}

__global__ void __launch_bounds__(256) fstep2_kernel(
    const float* __restrict__ h1, const int* __restrict__ off,
    const int* __restrict__ col, const float* __restrict__ inv,
    const float* __restrict__ Wl2, const float* __restrict__ bl2,
    const float* __restrict__ Wr2, const uint32_t* __restrict__ keys,
    int cid, int kf_idx,
    const int* __restrict__ users, const int* __restrict__ oh,
    const int* __restrict__ adj,
    const float* __restrict__ du, const float* __restrict__ di,
    const int* __restrict__ train, const int* __restrict__ neg,
    const float* __restrict__ l1, int round,
    int* __restrict__ gneg_out, float* __restrict__ out){
  __shared__ float sWlT[HH*DD2], sWrT[HH*DD2];
  __shared__ float rows[2+KN][DD2+1];
  __shared__ int nds[2+KN];
  __shared__ float ps[KN], lps[KN], rk[KN];
  __shared__ int nid[KN], cand[KN];
  __shared__ float msh[2];
  int t=threadIdx.x, lane=t&63, w=t>>6, b=blockIdx.x;
  for(int j=t;j<HH*DD2;j+=256){
    int k=j>>6, d=j&63;
    sWlT[j]=Wl2[d*HH+k]; sWrT[j]=Wr2[d*HH+k];
  }
  if(t==0){ nds[0]=users[b]; nds[1]=oh[b]; }
  if(t>=2 && t<2+KN) nds[t]=adj[(size_t)oh[b]*KN + (t-2)];
  __syncthreads();
  uint32_t k2a=keys[cid*4+2], k2b=keys[cid*4+3];
  for(int r=w; r<2+KN; r+=4)
    rows[r][lane]=g_row_core(nds[r],lane,h1,off,col,inv,sWlT,sWrT,bl2,k2a,k2b);
  __syncthreads();
  if(t<KN){
    float p=0.f;
    for(int d=0;d<DD2;++d) p += rows[2+t][d]*(rows[0][d]*rows[1][d]);
    ps[t]=p;
  }
  __syncthreads();
  if(t==0){
    float m=ps[0]; for(int k=1;k<KN;++k) m=fmaxf(m,ps[k]);
    float s=0.f;  for(int k=0;k<KN;++k) s += expf(ps[k]-m);
    msh[0]=m; msh[1]=logf(s);
    for(int k=0;k<KN;++k) nid[k]=k;
    for(int i=1;i<KN;++i){
      int v=nid[i]; float pv=ps[v]; int j=i-1;
      while(j>=0 && ps[nid[j]]>pv){ nid[j+1]=nid[j]; --j; }
      nid[j+1]=v;
    }
  }
  __syncthreads();
  if(t<KN){
    int n=t, c=nds[2+nid[n]];
    if(c<0 || c>49999){
      uint32_t i0=(uint32_t)(b*KN+n);
      const uint32_t* fk = keys + 16 + kf_idx*4;
      uint32_t hb = xorbits(fk[0], fk[1], i0);
      uint32_t lb = xorbits(fk[2], fk[3], i0);
      c=(int)(((hb%50000u)*17296u + (lb%50000u))%50000u);
    }
    cand[n]=c;
    lps[n]=(ps[nid[n]]-msh[0])-msh[1];
    int u=nds[0];
    float rr=0.f;
    for(int d=0;d<DD2;++d) rr += du[(size_t)u*DD2+d]*di[(size_t)c*DD2+d];
    rk[n]=rr;
  }
  __syncthreads();
  if(t==0){
    int best=0; float bv=rk[0];
    for(int n=1;n<KN;++n) if(rk[n]>bv){bv=rk[n];best=n;}
    int gn=cand[best]; float lsel=lps[best];
    bool it=false;
    for(int t2=0;t2<TT;++t2) if(train[(size_t)b*TT+t2]==gn){it=true;break;}
    if(it) gn=neg[b];
    gneg_out[b]=gn;
    out[b*2+round]        = (float)gn;
    out[BB*2 + b*2+round] = l1[b]+lsel;
  }
}

extern "C" void kernel_launch(void* const* d_in, const int* in_sizes, int n_in,
                              void* d_out, int out_size, void* d_ws, size_t ws_size,
                              hipStream_t stream) {
  const int*   users=(const int*)d_in[0];
  const int*   pos  =(const int*)d_in[1];
  const int*   neg  =(const int*)d_in[2];
  const int*   train=(const int*)d_in[3];
  const int*   adj  =(const int*)d_in[4];
  const int*   edge =(const int*)d_in[5];
  const float* ent  =(const float*)d_in[6];
  const float* Wl1  =(const float*)d_in[7];
  const float* bl1  =(const float*)d_in[8];
  const float* Wr1  =(const float*)d_in[9];
  const float* Wl2  =(const float*)d_in[10];
  const float* bl2  =(const float*)d_in[11];
  const float* Wr2  =(const float*)d_in[12];
  const float* du   =(const float*)d_in[13];
  const float* di   =(const float*)d_in[14];
  float* out=(float*)d_out;

  char* wsb=(char*)d_ws;
  size_t o=0;
  auto alloc=[&](size_t n)->char*{ char* p=wsb+o; o=(o+n+255)&~(size_t)255; return p; };
  uint32_t* keys=(uint32_t*)alloc(32*4);
  int*   bcnt=(int*)alloc((size_t)(NBUK+1)*4);
  int*   boff=(int*)alloc((size_t)(NBUK+1)*4);
  int*   bcur=(int*)alloc((size_t)NBUK*4);
  int*   ohb=(int*)alloc((size_t)BB*4);
  float* l1b=(float*)alloc((size_t)BB*4);
  int*   g1b=(int*)alloc((size_t)BB*4);
  int*   g2b=(int*)alloc((size_t)BB*4);
  int*   cnt=(int*)alloc((size_t)NND*4);
  int*   off=(int*)alloc((size_t)(NND+1)*4);
  int*   cur=(int*)alloc((size_t)NND*4);
  float* inv=(float*)alloc((size_t)NND*4);
  int*   col=(int*)alloc((size_t)NE*4);
  float* h1 =(float*)alloc((size_t)NND*HH*4);
  float* rowbuf=(float*)alloc((size_t)BB*NROWS*DD2*4);
  size_t o_rowbuf = o;
  float* h1base=(float*)alloc((size_t)NND*HH*4);
  int tier = (ws_size >= o) ? 2 : ((ws_size >= o_rowbuf) ? 1 : 0);
  ull* tmp8 = (ull*)rowbuf;   // aliases rowbuf+h1base (30.6MB >= 25.6MB); build precedes use

  keys_kernel<<<1,64,0,stream>>>(keys);

  if(tier==2){
    hipMemsetAsync(bcnt,0,(size_t)(NBUK+1)*4,stream);
    bcount_kernel<<<512,256,0,stream>>>(edge,bcnt);
    bscan_kernel<<<1,64,0,stream>>>(bcnt,boff,bcur,off);
    bscatter_kernel<<<512,256,0,stream>>>(edge,bcur,tmp8);
    bucket_csr_kernel<<<NBUK,256,0,stream>>>(boff,tmp8,off,inv,col);
  } else {
    hipMemsetAsync(cnt,0,(size_t)NND*4,stream);
    count_kernel<<<NE/256,256,0,stream>>>(edge,cnt);
    scan_kernel<<<1,1024,0,stream>>>(cnt,off,cur,inv);
    fill_kernel<<<NE/256,256,0,stream>>>(edge,cur,col);
  }
  sortseg_wave_kernel<<<NND/4,256,0,stream>>>(off,col);

  const int GROWS_GRID = BB*NROWS/4;
  const int MASK_GRID  = (NND*HH+255)/256;

  if(tier==2){
    sage1base_kernel<<<NND/4,256,0,stream>>>(ent,off,col,inv,Wl1,bl1,Wr1,h1base);
    for(int r=0;r<2;++r){
      const int* pid = (r==0)? pos : g1b;
      int cidA=2*r, cidB=2*r+1;
      mask_kernel<<<MASK_GRID,256,0,stream>>>(h1base,keys,cidA,h1);
      grows_kernel<<<GROWS_GRID,256,0,stream>>>(h1,off,col,inv,Wl2,bl2,Wr2,keys,cidA,
                                                users,pid,adj,rowbuf);
      sel1_kernel<<<BB,64,0,stream>>>(rowbuf,users,pid,adj,ohb,l1b);
      mask_kernel<<<MASK_GRID,256,0,stream>>>(h1base,keys,cidB,h1);
      grows_kernel<<<GROWS_GRID,256,0,stream>>>(h1,off,col,inv,Wl2,bl2,Wr2,keys,cidB,
                                                users,ohb,adj,rowbuf);
      sel2_kernel<<<BB,64,0,stream>>>(rowbuf,keys,r,users,ohb,adj,du,di,train,neg,l1b,r,
                                      (r==0)?g1b:g2b,out);
    }
  } else if(tier==1){
    for(int r=0;r<2;++r){
      const int* pid = (r==0)? pos : g1b;
      int cidA=2*r, cidB=2*r+1;
      sage1_kernel<<<NND/4,256,0,stream>>>(ent,off,col,inv,Wl1,bl1,Wr1,keys,cidA,h1);
      grows_kernel<<<GROWS_GRID,256,0,stream>>>(h1,off,col,inv,Wl2,bl2,Wr2,keys,cidA,
                                                users,pid,adj,rowbuf);
      sel1_kernel<<<BB,64,0,stream>>>(rowbuf,users,pid,adj,ohb,l1b);
      sage1_kernel<<<NND/4,256,0,stream>>>(ent,off,col,inv,Wl1,bl1,Wr1,keys,cidB,h1);
      grows_kernel<<<GROWS_GRID,256,0,stream>>>(h1,off,col,inv,Wl2,bl2,Wr2,keys,cidB,
                                                users,ohb,adj,rowbuf);
      sel2_kernel<<<BB,64,0,stream>>>(rowbuf,keys,r,users,ohb,adj,du,di,train,neg,l1b,r,
                                      (r==0)?g1b:g2b,out);
    }
  } else {
    for(int r=0;r<2;++r){
      const int* pid = (r==0)? pos : g1b;
      int cidA=2*r, cidB=2*r+1;
      sage1_kernel<<<NND/4,256,0,stream>>>(ent,off,col,inv,Wl1,bl1,Wr1,keys,cidA,h1);
      fstep1_kernel<<<BB,256,0,stream>>>(h1,off,col,inv,Wl2,bl2,Wr2,keys,cidA,
                                         users,pid,adj,ohb,l1b);
      sage1_kernel<<<NND/4,256,0,stream>>>(ent,off,col,inv,Wl1,bl1,Wr1,keys,cidB,h1);
      fstep2_kernel<<<BB,256,0,stream>>>(h1,off,col,inv,Wl2,bl2,Wr2,keys,cidB,r,
                                         users,ohb,adj,du,di,train,neg,l1b,r,
                                         (r==0)?g1b:g2b,out);
    }
  }
}

// Round 18
// 1042.597 us; speedup vs baseline: 3.5309x; 1.2755x over previous
//
#include <hip/hip_runtime.h>
#include <hip/hip_bf16.h>
#include <stdint.h>

#define NND 100000
#define KN 32
#define NE (NND*KN)
#define BB 2048
#define TT 50
#define DD0 64
#define HH 32
#define DD2 64
#define NROWS 34
#define BSH 9
#define NBUK ((NND + (1<<BSH) - 1) >> BSH)   // 196
#define PCHUNK 6250                           // NE / 512

typedef unsigned long long ull;

__device__ __forceinline__ void tf2x32(uint32_t k0, uint32_t k1, uint32_t& x0, uint32_t& x1){
  uint32_t k2 = k0 ^ k1 ^ 0x1BD11BDAu;
#define TFR(r) { x0 += x1; x1 = (x1<<(r)) | (x1>>(32-(r))); x1 ^= x0; }
  x0 += k0; x1 += k1;
  TFR(13) TFR(15) TFR(26) TFR(6)
  x0 += k1; x1 += k2 + 1u;
  TFR(17) TFR(29) TFR(16) TFR(24)
  x0 += k2; x1 += k0 + 2u;
  TFR(13) TFR(15) TFR(26) TFR(6)
  x0 += k0; x1 += k1 + 3u;
  TFR(17) TFR(29) TFR(16) TFR(24)
  x0 += k1; x1 += k2 + 4u;
  TFR(13) TFR(15) TFR(26) TFR(6)
  x0 += k2; x1 += k0 + 5u;
#undef TFR
}

__device__ __forceinline__ uint32_t xorbits(uint32_t ka, uint32_t kb, uint32_t i){
  uint32_t x0=0u, x1=i;
  tf2x32(ka,kb,x0,x1);
  return x0^x1;
}

__global__ void keys_kernel(uint32_t* keys, int* bcnt){
  int t=threadIdx.x;
  for(int i=t;i<NBUK+1;i+=64) bcnt[i]=0;
  if(t==0 && blockIdx.x==0){
    for(int cid=0;cid<4;++cid){
      uint32_t K0=0u,K1=(uint32_t)cid;
      tf2x32(0u,42u,K0,K1);
      uint32_t a0=0u,a1=0u; tf2x32(K0,K1,a0,a1);
      uint32_t b0=0u,b1=1u; tf2x32(K0,K1,b0,b1);
      keys[cid*4+0]=a0; keys[cid*4+1]=a1;
      keys[cid*4+2]=b0; keys[cid*4+3]=b1;
    }
    for(int r=0;r<2;++r){
      uint32_t F0=0u,F1=(uint32_t)(2*r);
      tf2x32(0u,7u,F0,F1);
      uint32_t a0=0u,a1=0u; tf2x32(F0,F1,a0,a1);
      uint32_t b0=0u,b1=1u; tf2x32(F0,F1,b0,b1);
      keys[16+r*4+0]=a0; keys[16+r*4+1]=a1;
      keys[16+r*4+2]=b0; keys[16+r*4+3]=b1;
    }
  }
}

// ===== bucketed CSR build =====
__global__ void __launch_bounds__(256) bcount_kernel(const int* __restrict__ edge, int* bcnt){
  __shared__ int h[NBUK];
  int t=threadIdx.x;
  for(int i=t;i<NBUK;i+=256) h[i]=0;
  __syncthreads();
  int start=blockIdx.x*PCHUNK, end=start+PCHUNK;
  for(int e=start+t;e<end;e+=256) atomicAdd(&h[edge[e]>>BSH],1);
  __syncthreads();
  for(int i=t;i<NBUK;i+=256) if(h[i]) atomicAdd(&bcnt[i],h[i]);
}

__global__ void bscan_kernel(const int* bcnt, int* boff, int* bcur, int* off){
  if(threadIdx.x==0 && blockIdx.x==0){
    int run=0;
    for(int i=0;i<NBUK;++i){ boff[i]=run; bcur[i]=run; run+=bcnt[i]; }
    boff[NBUK]=run;
    off[NND]=NE;
  }
}

__global__ void __launch_bounds__(256) bscatter_kernel(const int* __restrict__ edge,
    int* bcur, ull* __restrict__ tmp8){
  __shared__ int h[NBUK], base[NBUK], lcur[NBUK];
  int t=threadIdx.x;
  for(int i=t;i<NBUK;i+=256){ h[i]=0; lcur[i]=0; }
  __syncthreads();
  int start=blockIdx.x*PCHUNK, end=start+PCHUNK;
  for(int e=start+t;e<end;e+=256) atomicAdd(&h[edge[e]>>BSH],1);
  __syncthreads();
  for(int i=t;i<NBUK;i+=256) base[i] = h[i]? atomicAdd(&bcur[i],h[i]) : 0;
  __syncthreads();
  for(int e=start+t;e<end;e+=256){
    int d=edge[e];
    int b=d>>BSH;
    int r=atomicAdd(&lcur[b],1);
    tmp8[base[b]+r] = (((ull)(unsigned)d)<<32) | (unsigned)e;
  }
}

__global__ void __launch_bounds__(256) bucket_csr_kernel(const int* __restrict__ boff,
    const ull* __restrict__ tmp8, int* __restrict__ off, float* __restrict__ inv,
    int* __restrict__ col){
  __shared__ int cnt[512], pref[512], cur2[512];
  int b=blockIdx.x, t=threadIdx.x;
  int nb=b<<BSH;
  for(int i=t;i<512;i+=256) cnt[i]=0;
  __syncthreads();
  int lo=boff[b], hi=boff[b+1];
  for(int i=lo+t;i<hi;i+=256){
    int ld=(int)(tmp8[i]>>32)-nb;
    atomicAdd(&cnt[ld],1);
  }
  __syncthreads();
  if(t==0){ int run=lo; for(int i=0;i<512;++i){ pref[i]=run; cur2[i]=run; run+=cnt[i]; } }
  __syncthreads();
  for(int i=t;i<512;i+=256){
    int d=nb+i;
    if(d<NND){ off[d]=pref[i]; int c=cnt[i]; inv[d]=1.0f/(float)(c>0?c:1); }
  }
  __syncthreads();
  for(int i=lo+t;i<hi;i+=256){
    ull v=tmp8[i];
    int ld=(int)(v>>32)-nb;
    int r=atomicAdd(&cur2[ld],1);
    col[r]=(int)(v&0xffffffffu);
  }
}

// ===== fallback build =====
__global__ void count_kernel(const int* dst, int* cnt){
  int e = blockIdx.x*256 + threadIdx.x;
  if(e < NE) atomicAdd(&cnt[dst[e]], 1);
}
__global__ void scan_kernel(const int* cnt, int* off, int* cur, float* inv){
  __shared__ int part[1024];
  int t = threadIdx.x;
  const int CH = (NND + 1023)/1024;
  int lo = t*CH, hi = lo+CH; if(hi>NND) hi=NND;
  int s=0;
  for(int i=lo;i<hi;++i) s += cnt[i];
  part[t]=s;
  __syncthreads();
  if(t==0){ int run=0; for(int i=0;i<1024;++i){ int v=part[i]; part[i]=run; run+=v; } }
  __syncthreads();
  int run = part[t];
  for(int i=lo;i<hi;++i){
    off[i]=run; cur[i]=run;
    int c=cnt[i];
    inv[i]=1.0f/(float)(c>0?c:1);
    run+=c;
  }
  if(t==0) off[NND]=NE;
}
__global__ void fill_kernel(const int* dst, int* cur, int* col){
  int e = blockIdx.x*256 + threadIdx.x;
  if(e < NE){
    int d = dst[e];
    int slot = atomicAdd(&cur[d],1);
    col[slot] = e;
  }
}

// wave odd-even sort of each CSR segment
__global__ void __launch_bounds__(256) sortseg_wave_kernel(const int* off, int* col){
  int t=threadIdx.x, lane=t&63, w=t>>6;
  int node = blockIdx.x*4 + w;
  if(node>=NND) return;
  int lo=off[node], hi=off[node+1];
  int deg=hi-lo;
  if(deg<=1) return;
  if(deg<=64){
    int v = (lane<deg)? col[lo+lane] : 0x7fffffff;
    for(int p=0;p<64;++p){
      int partner;
      if((p&1)==0) partner = lane^1;
      else partner = (lane==0||lane==63)? lane : ((lane&1)? lane+1 : lane-1);
      int pv = __shfl(v, partner, 64);
      if(partner>lane) v = v<pv? v:pv;
      else if(partner<lane) v = v>pv? v:pv;
    }
    if(lane<deg) col[lo+lane]=v;
  } else if(lane==0){
    for(int i=lo+1;i<hi;++i){
      int v=col[i]; int j=i-1;
      while(j>=lo && col[j]>v){ col[j+1]=col[j]; --j; }
      col[j+1]=v;
    }
  }
}

// order-preserving 16-deep batched gather (FP order identical to sequential loop)
__device__ __forceinline__ float gather_seq(const float* __restrict__ src, int S, int d,
    const int* __restrict__ col, int lo, int hi, int lane){
  float acc=0.f;
  int deg=hi-lo, base=0;
  while(base<deg){
    int rem=deg-base; int cw = rem<64?rem:64;
    int cv = col[lo+base+ (lane<cw?lane:cw-1)];
    for(int k=0;k<cw;k+=16){
      int m=cw-k;
      float v[16];
#pragma unroll
      for(int j=0;j<16;++j){
        int q = (j<m)? k+j : k;
        int s = __shfl(cv,q,64)>>5;
        v[j] = src[(size_t)s*S+d];
      }
#pragma unroll
      for(int j=0;j<16;++j) if(j<m) acc += v[j];
    }
    base+=cw;
  }
  return acc;
}

// h1base = leaky_relu(agg@Wl1.T + bl1 + x@Wr1.T); 512 threads, 8 nodes/block
__global__ void __launch_bounds__(512) sage1base_kernel(const float* __restrict__ x,
    const int* __restrict__ off, const int* __restrict__ col,
    const float* __restrict__ inv, const float* __restrict__ Wl,
    const float* __restrict__ bl, const float* __restrict__ Wr,
    float* __restrict__ h1base){
  __shared__ float sWlT[DD0*HH], sWrT[DD0*HH];
  __shared__ float sA[8][DD0], sX[8][DD0];
  int t=threadIdx.x, lane=t&63, w=t>>6;
  for(int j=t;j<HH*DD0;j+=512){
    int k=j>>5, h=j&31;
    sWlT[j]=Wl[h*DD0+k]; sWrT[j]=Wr[h*DD0+k];
  }
  int node=blockIdx.x*8+w;
  int lo=off[node], hi=off[node+1];
  float acc=gather_seq(x,DD0,lane,col,lo,hi,lane);
  acc *= inv[node];
  sA[w][lane]=acc;
  sX[w][lane]=x[(size_t)node*DD0+lane];
  __syncthreads();
  if(lane<HH){
    float s1=0.f, s2=0.f;
    for(int k=0;k<DD0;++k){
      s1 += sA[w][k]*sWlT[k*HH+lane];
      s2 += sX[w][k]*sWrT[k*HH+lane];
    }
    float v=s1+bl[lane]+s2;
    v = (v>=0.f) ? v : 0.01f*v;
    h1base[(size_t)node*HH+lane]=v;
  }
}

__global__ void __launch_bounds__(256) mask_kernel(const float* __restrict__ h1base,
    const uint32_t* __restrict__ keys, int cid, float* __restrict__ h1){
  int j = blockIdx.x*256 + threadIdx.x;
  if(j < NND*HH){
    uint32_t bits = xorbits(keys[cid*4+0],keys[cid*4+1],(uint32_t)j);
    float v = h1base[j];
    h1[j] = ((bits>>31)==0u) ? 2.f*v : 0.f;
  }
}

// full sage1 (fallback tiers)
__global__ void __launch_bounds__(256) sage1_kernel(const float* __restrict__ x,
    const int* __restrict__ off, const int* __restrict__ col,
    const float* __restrict__ inv, const float* __restrict__ Wl,
    const float* __restrict__ bl, const float* __restrict__ Wr,
    const uint32_t* __restrict__ keys, int cid, float* __restrict__ h1o){
  __shared__ float sWlT[DD0*HH], sWrT[DD0*HH];
  __shared__ float sA[4][DD0], sX[4][DD0];
  int t=threadIdx.x, lane=t&63, w=t>>6;
  for(int j=t;j<HH*DD0;j+=256){
    int k=j>>5, h=j&31;
    sWlT[j]=Wl[h*DD0+k]; sWrT[j]=Wr[h*DD0+k];
  }
  int node=blockIdx.x*4+w;
  int lo=off[node], hi=off[node+1];
  float acc=gather_seq(x,DD0,lane,col,lo,hi,lane);
  acc *= inv[node];
  sA[w][lane]=acc;
  sX[w][lane]=x[(size_t)node*DD0+lane];
  __syncthreads();
  if(lane<HH){
    float s1=0.f, s2=0.f;
    for(int k=0;k<DD0;++k){
      s1 += sA[w][k]*sWlT[k*HH+lane];
      s2 += sX[w][k]*sWrT[k*HH+lane];
    }
    float v=s1+bl[lane]+s2;
    v = (v>=0.f) ? v : 0.01f*v;
    uint32_t j=(uint32_t)(node*HH+lane);
    uint32_t bits = xorbits(keys[cid*4+0],keys[cid*4+1],j);
    v = ((bits>>31)==0u) ? 2.f*v : 0.f;
    h1o[(size_t)node*HH+lane]=v;
  }
}

__device__ __forceinline__ float g_row_core(int n, int lane,
    const float* __restrict__ h1, const int* __restrict__ off,
    const int* __restrict__ col, const float* __restrict__ inv,
    const float* __restrict__ sWlT, const float* __restrict__ sWrT,
    const float* __restrict__ bl2, uint32_t k2a, uint32_t k2b){
  int lo=off[n], hi=off[n+1];
  int d=lane&31;
  float acc=gather_seq(h1,HH,d,col,lo,hi,lane);
  float aggd = acc*inv[n];
  float hd   = h1[(size_t)n*HH+d];
  float s1=0.f, s2=0.f;
  for(int k=0;k<HH;++k){
    float ak=__shfl(aggd,k,64);
    float hk=__shfl(hd,k,64);
    s1 += ak*sWlT[k*DD2+lane];
    s2 += hk*sWrT[k*DD2+lane];
  }
  float v=s1+bl2[lane]+s2;
  uint32_t j=(uint32_t)n*64u+(uint32_t)lane;
  uint32_t bits = xorbits(k2a,k2b,j);
  v = ((bits>>31)==0u) ? 2.f*v : 0.f;
  float ss=v*v;
  for(int m=1;m<64;m<<=1) ss += __shfl_xor(ss,m,64);
  return v/fmaxf(sqrtf(ss),1e-12f);
}

// one wave per g-row; 512 threads, 8 rows/block; grid = BB*NROWS/8
__global__ void __launch_bounds__(512) grows_kernel(
    const float* __restrict__ h1, const int* __restrict__ off,
    const int* __restrict__ col, const float* __restrict__ inv,
    const float* __restrict__ Wl2, const float* __restrict__ bl2,
    const float* __restrict__ Wr2, const uint32_t* __restrict__ keys, int cid,
    const int* __restrict__ users, const int* __restrict__ pid_arr,
    const int* __restrict__ adj, float* __restrict__ rowbuf){
  __shared__ float sWlT[HH*DD2], sWrT[HH*DD2];
  int t=threadIdx.x, lane=t&63, w=t>>6;
  for(int j=t;j<HH*DD2;j+=512){
    int k=j>>6, d=j&63;
    sWlT[j]=Wl2[d*HH+k]; sWrT[j]=Wr2[d*HH+k];
  }
  __syncthreads();
  int wg = blockIdx.x*8 + w;
  if(wg >= BB*NROWS) return;
  int b = wg/NROWS, r = wg - b*NROWS;
  int pid = pid_arr[b];
  int node = (r==0)? users[b] : ((r==1)? pid : adj[(size_t)pid*KN + (r-2)]);
  uint32_t k2a=keys[cid*4+2], k2b=keys[cid*4+3];
  float v = g_row_core(node,lane,h1,off,col,inv,sWlT,sWrT,bl2,k2a,k2b);
  rowbuf[(size_t)wg*DD2 + lane] = v;
}

__global__ void __launch_bounds__(64) sel1_kernel(
    const float* __restrict__ rowbuf,
    const int* __restrict__ users, const int* __restrict__ pid_arr,
    const int* __restrict__ adj, int* __restrict__ oh_out, float* __restrict__ l1_out){
  int b=blockIdx.x, t=threadIdx.x;
  __shared__ float wsh[DD2];
  __shared__ float ps[KN];
  const float* rb = rowbuf + (size_t)b*NROWS*DD2;
  wsh[t] = rb[t]*rb[DD2+t];
  __syncthreads();
  if(t<KN){
    float p=0.f;
    const float* rr = rb + (size_t)(2+t)*DD2;
    for(int d=0;d<DD2;++d) p += rr[d]*wsh[d];
    ps[t]=p;
  }
  __syncthreads();
  if(t==0){
    float m=ps[0]; for(int k=1;k<KN;++k) m=fmaxf(m,ps[k]);
    float s=0.f;  for(int k=0;k<KN;++k) s += expf(ps[k]-m);
    int best=0; float bv=ps[0];
    for(int k=1;k<KN;++k) if(ps[k]>bv){bv=ps[k];best=k;}
    oh_out[b]=adj[(size_t)pid_arr[b]*KN+best];
    l1_out[b]=(ps[best]-m)-logf(s);
  }
}

__global__ void __launch_bounds__(64) sel2_kernel(
    const float* __restrict__ rowbuf, const uint32_t* __restrict__ keys, int kf_idx,
    const int* __restrict__ users, const int* __restrict__ oh,
    const int* __restrict__ adj,
    const float* __restrict__ du, const float* __restrict__ di,
    const int* __restrict__ train, const int* __restrict__ neg,
    const float* __restrict__ l1, int round,
    int* __restrict__ gneg_out, float* __restrict__ out){
  int b=blockIdx.x, t=threadIdx.x;
  __shared__ float wsh[DD2];
  __shared__ float ps[KN], lps[KN], rk[KN];
  __shared__ int nid[KN], cand[KN];
  __shared__ float msh[2];
  const float* rb = rowbuf + (size_t)b*NROWS*DD2;
  wsh[t] = rb[t]*rb[DD2+t];
  __syncthreads();
  if(t<KN){
    float p=0.f;
    const float* rr = rb + (size_t)(2+t)*DD2;
    for(int d=0;d<DD2;++d) p += rr[d]*wsh[d];
    ps[t]=p;
  }
  __syncthreads();
  if(t==0){
    float m=ps[0]; for(int k=1;k<KN;++k) m=fmaxf(m,ps[k]);
    float s=0.f;  for(int k=0;k<KN;++k) s += expf(ps[k]-m);
    msh[0]=m; msh[1]=logf(s);
    for(int k=0;k<KN;++k) nid[k]=k;
    for(int i=1;i<KN;++i){
      int v=nid[i]; float pv=ps[v]; int j=i-1;
      while(j>=0 && ps[nid[j]]>pv){ nid[j+1]=nid[j]; --j; }
      nid[j+1]=v;
    }
  }
  __syncthreads();
  if(t<KN){
    int n=t, c=adj[(size_t)oh[b]*KN + nid[n]];
    if(c<0 || c>49999){
      uint32_t i0=(uint32_t)(b*KN+n);
      const uint32_t* fk = keys + 16 + kf_idx*4;
      uint32_t hb = xorbits(fk[0], fk[1], i0);
      uint32_t lb = xorbits(fk[2], fk[3], i0);
      c=(int)(((hb%50000u)*17296u + (lb%50000u))%50000u);
    }
    cand[n]=c;
    lps[n]=(ps[nid[n]]-msh[0])-msh[1];
    int u=users[b];
    float rr=0.f;
    for(int d=0;d<DD2;++d) rr += du[(size_t)u*DD2+d]*di[(size_t)c*DD2+d];
    rk[n]=rr;
  }
  __syncthreads();
  if(t==0){
    int best=0; float bv=rk[0];
    for(int n=1;n<KN;++n) if(rk[n]>bv){bv=rk[n];best=n;}
    int gn=cand[best]; float lsel=lps[best];
    bool it=false;
    for(int t2=0;t2<TT;++t2) if(train[(size_t)b*TT+t2]==gn){it=true;break;}
    if(it) gn=neg[b];
    gneg_out[b]=gn;
    out[b*2+round]        = (float)gn;
    out[BB*2 + b*2+round] = l1[b]+lsel;
  }
}

// ===== fallback fused steps (tier 0) =====
__global__ void __launch_bounds__(256) fstep1_kernel(
    const float* __restrict__ h1, const int* __restrict__ off,
    const int* __restrict__ col, const float* __restrict__ inv,
    const float* __restrict__ Wl2, const float* __restrict__ bl2,
    const float* __restrict__ Wr2, const uint32_t* __restrict__ keys, int cid,
    const int* __restrict__ users, const int* __restrict__ pid_arr,
    const int* __restrict__ adj, int* __restrict__ oh_out, float* __restrict__ l1_out){
  __shared__ float sWlT[HH*DD2], sWrT[HH*DD2];
  __shared__ float rows[2+KN][DD2+1];
  __shared__ int nds[2+KN];
  __shared__ float ps[KN];
  int t=threadIdx.x, lane=t&63, w=t>>6, b=blockIdx.x;
  for(int j=t;j<HH*DD2;j+=256){
    int k=j>>6, d=j&63;
    sWlT[j]=Wl2[d*HH+k]; sWrT[j]=Wr2[d*HH+k];
  }
  if(t==0){ nds[0]=users[b]; nds[1]=pid_arr[b]; }
  if(t>=2 && t<2+KN) nds[t]=adj[(size_t)pid_arr[b]*KN + (t-2)];
  __syncthreads();
  uint32_t k2a=keys[cid*4+2], k2b=keys[cid*4+3];
  for(int r=w; r<2+KN; r+=4)
    rows[r][lane]=g_row_core(nds[r],lane,h1,off,col,inv,sWlT,sWrT,bl2,k2a,k2b);
  __syncthreads();
  if(t<KN){
    float p=0.f;
    for(int d=0;d<DD2;++d) p += rows[2+t][d]*(rows[0][d]*rows[1][d]);
    ps[t]=p;
  }
  __syncthreads();
  if(t==0){
    float m=ps[0]; for(int k=1;k<KN;++k) m=fmaxf(m,ps[k]);
    float s=0.f;  for(int k=0;k<KN;++k) s += expf(ps[k]-m);
    int best=0; float bv=ps[0];
    for(int k=1;k<KN;++k) if(ps[k]>bv){bv=ps[k];best=k;}
    oh_out[b]=nds[2+best];
    l1_out[b]=(ps[best]-m)-logf(s);
  }
}

__global__ void __launch_bounds__(256) fstep2_kernel(
    const float* __restrict__ h1, const int* __restrict__ off,
    const int* __restrict__ col, const float* __restrict__ inv,
    const float* __restrict__ Wl2, const float* __restrict__ bl2,
    const float* __restrict__ Wr2, const uint32_t* __restrict__ keys,
    int cid, int kf_idx,
    const int* __restrict__ users, const int* __restrict__ oh,
    const int* __restrict__ adj,
    const float* __restrict__ du, const float* __restrict__ di,
    const int* __restrict__ train, const int* __restrict__ neg,
    const float* __restrict__ l1, int round,
    int* __restrict__ gneg_out, float* __restrict__ out){
  __shared__ float sWlT[HH*DD2], sWrT[HH*DD2];
  __shared__ float rows[2+KN][DD2+1];
  __shared__ int nds[2+KN];
  __shared__ float ps[KN], lps[KN], rk[KN];
  __shared__ int nid[KN], cand[KN];
  __shared__ float msh[2];
  int t=threadIdx.x, lane=t&63, w=t>>6, b=blockIdx.x;
  for(int j=t;j<HH*DD2;j+=256){
    int k=j>>6, d=j&63;
    sWlT[j]=Wl2[d*HH+k]; sWrT[j]=Wr2[d*HH+k];
  }
  if(t==0){ nds[0]=users[b]; nds[1]=oh[b]; }
  if(t>=2 && t<2+KN) nds[t]=adj[(size_t)oh[b]*KN + (t-2)];
  __syncthreads();
  uint32_t k2a=keys[cid*4+2], k2b=keys[cid*4+3];
  for(int r=w; r<2+KN; r+=4)
    rows[r][lane]=g_row_core(nds[r],lane,h1,off,col,inv,sWlT,sWrT,bl2,k2a,k2b);
  __syncthreads();
  if(t<KN){
    float p=0.f;
    for(int d=0;d<DD2;++d) p += rows[2+t][d]*(rows[0][d]*rows[1][d]);
    ps[t]=p;
  }
  __syncthreads();
  if(t==0){
    float m=ps[0]; for(int k=1;k<KN;++k) m=fmaxf(m,ps[k]);
    float s=0.f;  for(int k=0;k<KN;++k) s += expf(ps[k]-m);
    msh[0]=m; msh[1]=logf(s);
    for(int k=0;k<KN;++k) nid[k]=k;
    for(int i=1;i<KN;++i){
      int v=nid[i]; float pv=ps[v]; int j=i-1;
      while(j>=0 && ps[nid[j]]>pv){ nid[j+1]=nid[j]; --j; }
      nid[j+1]=v;
    }
  }
  __syncthreads();
  if(t<KN){
    int n=t, c=nds[2+nid[n]];
    if(c<0 || c>49999){
      uint32_t i0=(uint32_t)(b*KN+n);
      const uint32_t* fk = keys + 16 + kf_idx*4;
      uint32_t hb = xorbits(fk[0], fk[1], i0);
      uint32_t lb = xorbits(fk[2], fk[3], i0);
      c=(int)(((hb%50000u)*17296u + (lb%50000u))%50000u);
    }
    cand[n]=c;
    lps[n]=(ps[nid[n]]-msh[0])-msh[1];
    int u=nds[0];
    float rr=0.f;
    for(int d=0;d<DD2;++d) rr += du[(size_t)u*DD2+d]*di[(size_t)c*DD2+d];
    rk[n]=rr;
  }
  __syncthreads();
  if(t==0){
    int best=0; float bv=rk[0];
    for(int n=1;n<KN;++n) if(rk[n]>bv){bv=rk[n];best=n;}
    int gn=cand[best]; float lsel=lps[best];
    bool it=false;
    for(int t2=0;t2<TT;++t2) if(train[(size_t)b*TT+t2]==gn){it=true;break;}
    if(it) gn=neg[b];
    gneg_out[b]=gn;
    out[b*2+round]        = (float)gn;
    out[BB*2 + b*2+round] = l1[b]+lsel;
  }
}

extern "C" void kernel_launch(void* const* d_in, const int* in_sizes, int n_in,
                              void* d_out, int out_size, void* d_ws, size_t ws_size,
                              hipStream_t stream) {
  const int*   users=(const int*)d_in[0];
  const int*   pos  =(const int*)d_in[1];
  const int*   neg  =(const int*)d_in[2];
  const int*   train=(const int*)d_in[3];
  const int*   adj  =(const int*)d_in[4];
  const int*   edge =(const int*)d_in[5];
  const float* ent  =(const float*)d_in[6];
  const float* Wl1  =(const float*)d_in[7];
  const float* bl1  =(const float*)d_in[8];
  const float* Wr1  =(const float*)d_in[9];
  const float* Wl2  =(const float*)d_in[10];
  const float* bl2  =(const float*)d_in[11];
  const float* Wr2  =(const float*)d_in[12];
  const float* du   =(const float*)d_in[13];
  const float* di   =(const float*)d_in[14];
  float* out=(float*)d_out;

  char* wsb=(char*)d_ws;
  size_t o=0;
  auto alloc=[&](size_t n)->char*{ char* p=wsb+o; o=(o+n+255)&~(size_t)255; return p; };
  uint32_t* keys=(uint32_t*)alloc(32*4);
  int*   bcnt=(int*)alloc((size_t)(NBUK+1)*4);
  int*   boff=(int*)alloc((size_t)(NBUK+1)*4);
  int*   bcur=(int*)alloc((size_t)NBUK*4);
  int*   ohb=(int*)alloc((size_t)BB*4);
  float* l1b=(float*)alloc((size_t)BB*4);
  int*   g1b=(int*)alloc((size_t)BB*4);
  int*   g2b=(int*)alloc((size_t)BB*4);
  int*   cnt=(int*)alloc((size_t)NND*4);
  int*   off=(int*)alloc((size_t)(NND+1)*4);
  int*   cur=(int*)alloc((size_t)NND*4);
  float* inv=(float*)alloc((size_t)NND*4);
  int*   col=(int*)alloc((size_t)NE*4);
  float* h1 =(float*)alloc((size_t)NND*HH*4);
  float* rowbuf=(float*)alloc((size_t)BB*NROWS*DD2*4);
  size_t o_rowbuf = o;
  float* h1base=(float*)alloc((size_t)NND*HH*4);
  int tier = (ws_size >= o) ? 2 : ((ws_size >= o_rowbuf) ? 1 : 0);
  ull* tmp8 = (ull*)rowbuf;   // aliases rowbuf+h1base; build precedes their use

  keys_kernel<<<1,64,0,stream>>>(keys,bcnt);

  if(tier==2){
    bcount_kernel<<<512,256,0,stream>>>(edge,bcnt);
    bscan_kernel<<<1,64,0,stream>>>(bcnt,boff,bcur,off);
    bscatter_kernel<<<512,256,0,stream>>>(edge,bcur,tmp8);
    bucket_csr_kernel<<<NBUK,256,0,stream>>>(boff,tmp8,off,inv,col);
  } else {
    hipMemsetAsync(cnt,0,(size_t)NND*4,stream);
    count_kernel<<<NE/256,256,0,stream>>>(edge,cnt);
    scan_kernel<<<1,1024,0,stream>>>(cnt,off,cur,inv);
    fill_kernel<<<NE/256,256,0,stream>>>(edge,cur,col);
  }
  sortseg_wave_kernel<<<NND/4,256,0,stream>>>(off,col);

  const int GROWS_GRID = (BB*NROWS+7)/8;
  const int MASK_GRID  = (NND*HH+255)/256;

  if(tier==2){
    sage1base_kernel<<<NND/8,512,0,stream>>>(ent,off,col,inv,Wl1,bl1,Wr1,h1base);
    for(int r=0;r<2;++r){
      const int* pid = (r==0)? pos : g1b;
      int cidA=2*r, cidB=2*r+1;
      mask_kernel<<<MASK_GRID,256,0,stream>>>(h1base,keys,cidA,h1);
      grows_kernel<<<GROWS_GRID,512,0,stream>>>(h1,off,col,inv,Wl2,bl2,Wr2,keys,cidA,
                                                users,pid,adj,rowbuf);
      sel1_kernel<<<BB,64,0,stream>>>(rowbuf,users,pid,adj,ohb,l1b);
      mask_kernel<<<MASK_GRID,256,0,stream>>>(h1base,keys,cidB,h1);
      grows_kernel<<<GROWS_GRID,512,0,stream>>>(h1,off,col,inv,Wl2,bl2,Wr2,keys,cidB,
                                                users,ohb,adj,rowbuf);
      sel2_kernel<<<BB,64,0,stream>>>(rowbuf,keys,r,users,ohb,adj,du,di,train,neg,l1b,r,
                                      (r==0)?g1b:g2b,out);
    }
  } else if(tier==1){
    for(int r=0;r<2;++r){
      const int* pid = (r==0)? pos : g1b;
      int cidA=2*r, cidB=2*r+1;
      sage1_kernel<<<NND/4,256,0,stream>>>(ent,off,col,inv,Wl1,bl1,Wr1,keys,cidA,h1);
      grows_kernel<<<GROWS_GRID,512,0,stream>>>(h1,off,col,inv,Wl2,bl2,Wr2,keys,cidA,
                                                users,pid,adj,rowbuf);
      sel1_kernel<<<BB,64,0,stream>>>(rowbuf,users,pid,adj,ohb,l1b);
      sage1_kernel<<<NND/4,256,0,stream>>>(ent,off,col,inv,Wl1,bl1,Wr1,keys,cidB,h1);
      grows_kernel<<<GROWS_GRID,512,0,stream>>>(h1,off,col,inv,Wl2,bl2,Wr2,keys,cidB,
                                                users,ohb,adj,rowbuf);
      sel2_kernel<<<BB,64,0,stream>>>(rowbuf,keys,r,users,ohb,adj,du,di,train,neg,l1b,r,
                                      (r==0)?g1b:g2b,out);
    }
  } else {
    for(int r=0;r<2;++r){
      const int* pid = (r==0)? pos : g1b;
      int cidA=2*r, cidB=2*r+1;
      sage1_kernel<<<NND/4,256,0,stream>>>(ent,off,col,inv,Wl1,bl1,Wr1,keys,cidA,h1);
      fstep1_kernel<<<BB,256,0,stream>>>(h1,off,col,inv,Wl2,bl2,Wr2,keys,cidA,
                                         users,pid,adj,ohb,l1b);
      sage1_kernel<<<NND/4,256,0,stream>>>(ent,off,col,inv,Wl1,bl1,Wr1,keys,cidB,h1);
      fstep2_kernel<<<BB,256,0,stream>>>(h1,off,col,inv,Wl2,bl2,Wr2,keys,cidB,r,
                                         users,ohb,adj,du,di,train,neg,l1b,r,
                                         (r==0)?g1b:g2b,out);
    }
  }
}

// Round 19
// 855.398 us; speedup vs baseline: 4.3036x; 1.2188x over previous
//
#include <hip/hip_runtime.h>
#include <hip/hip_bf16.h>
#include <stdint.h>

#define NND 100000
#define KN 32
#define NE (NND*KN)
#define BB 2048
#define TT 50
#define DD0 64
#define HH 32
#define DD2 64
#define NROWS 34
#define BSH 9
#define NBUK ((NND + (1<<BSH) - 1) >> BSH)   // 196
#define PCHUNK 6250                           // NE / 512

typedef unsigned long long ull;

__device__ __forceinline__ void tf2x32(uint32_t k0, uint32_t k1, uint32_t& x0, uint32_t& x1){
  uint32_t k2 = k0 ^ k1 ^ 0x1BD11BDAu;
#define TFR(r) { x0 += x1; x1 = (x1<<(r)) | (x1>>(32-(r))); x1 ^= x0; }
  x0 += k0; x1 += k1;
  TFR(13) TFR(15) TFR(26) TFR(6)
  x0 += k1; x1 += k2 + 1u;
  TFR(17) TFR(29) TFR(16) TFR(24)
  x0 += k2; x1 += k0 + 2u;
  TFR(13) TFR(15) TFR(26) TFR(6)
  x0 += k0; x1 += k1 + 3u;
  TFR(17) TFR(29) TFR(16) TFR(24)
  x0 += k1; x1 += k2 + 4u;
  TFR(13) TFR(15) TFR(26) TFR(6)
  x0 += k2; x1 += k0 + 5u;
#undef TFR
}

__device__ __forceinline__ uint32_t xorbits(uint32_t ka, uint32_t kb, uint32_t i){
  uint32_t x0=0u, x1=i;
  tf2x32(ka,kb,x0,x1);
  return x0^x1;
}

__global__ void keys_kernel(uint32_t* keys, int* bcnt){
  int t=threadIdx.x;
  for(int i=t;i<NBUK+1;i+=64) bcnt[i]=0;
  if(t==0 && blockIdx.x==0){
    for(int cid=0;cid<4;++cid){
      uint32_t K0=0u,K1=(uint32_t)cid;
      tf2x32(0u,42u,K0,K1);
      uint32_t a0=0u,a1=0u; tf2x32(K0,K1,a0,a1);
      uint32_t b0=0u,b1=1u; tf2x32(K0,K1,b0,b1);
      keys[cid*4+0]=a0; keys[cid*4+1]=a1;
      keys[cid*4+2]=b0; keys[cid*4+3]=b1;
    }
    for(int r=0;r<2;++r){
      uint32_t F0=0u,F1=(uint32_t)(2*r);
      tf2x32(0u,7u,F0,F1);
      uint32_t a0=0u,a1=0u; tf2x32(F0,F1,a0,a1);
      uint32_t b0=0u,b1=1u; tf2x32(F0,F1,b0,b1);
      keys[16+r*4+0]=a0; keys[16+r*4+1]=a1;
      keys[16+r*4+2]=b0; keys[16+r*4+3]=b1;
    }
  }
}

// ===== bucketed CSR build =====
__global__ void __launch_bounds__(256) bcount_kernel(const int* __restrict__ edge, int* bcnt){
  __shared__ int h[NBUK];
  int t=threadIdx.x;
  for(int i=t;i<NBUK;i+=256) h[i]=0;
  __syncthreads();
  int start=blockIdx.x*PCHUNK, end=start+PCHUNK;
  for(int e=start+t;e<end;e+=256) atomicAdd(&h[edge[e]>>BSH],1);
  __syncthreads();
  for(int i=t;i<NBUK;i+=256) if(h[i]) atomicAdd(&bcnt[i],h[i]);
}

__global__ void bscan_kernel(const int* bcnt, int* boff, int* bcur, int* off){
  if(threadIdx.x==0 && blockIdx.x==0){
    int run=0;
    for(int i=0;i<NBUK;++i){ boff[i]=run; bcur[i]=run; run+=bcnt[i]; }
    boff[NBUK]=run;
    off[NND]=NE;
  }
}

__global__ void __launch_bounds__(256) bscatter_kernel(const int* __restrict__ edge,
    int* bcur, ull* __restrict__ tmp8){
  __shared__ int h[NBUK], base[NBUK], lcur[NBUK];
  int t=threadIdx.x;
  for(int i=t;i<NBUK;i+=256){ h[i]=0; lcur[i]=0; }
  __syncthreads();
  int start=blockIdx.x*PCHUNK, end=start+PCHUNK;
  for(int e=start+t;e<end;e+=256) atomicAdd(&h[edge[e]>>BSH],1);
  __syncthreads();
  for(int i=t;i<NBUK;i+=256) base[i] = h[i]? atomicAdd(&bcur[i],h[i]) : 0;
  __syncthreads();
  for(int e=start+t;e<end;e+=256){
    int d=edge[e];
    int b=d>>BSH;
    int r=atomicAdd(&lcur[b],1);
    tmp8[base[b]+r] = (((ull)(unsigned)d)<<32) | (unsigned)e;
  }
}

__global__ void __launch_bounds__(256) bucket_csr_kernel(const int* __restrict__ boff,
    const ull* __restrict__ tmp8, int* __restrict__ off, float* __restrict__ inv,
    int* __restrict__ col){
  __shared__ int cnt[512], pref[512], cur2[512];
  int b=blockIdx.x, t=threadIdx.x;
  int nb=b<<BSH;
  for(int i=t;i<512;i+=256) cnt[i]=0;
  __syncthreads();
  int lo=boff[b], hi=boff[b+1];
  for(int i=lo+t;i<hi;i+=256){
    int ld=(int)(tmp8[i]>>32)-nb;
    atomicAdd(&cnt[ld],1);
  }
  __syncthreads();
  if(t==0){ int run=lo; for(int i=0;i<512;++i){ pref[i]=run; cur2[i]=run; run+=cnt[i]; } }
  __syncthreads();
  for(int i=t;i<512;i+=256){
    int d=nb+i;
    if(d<NND){ off[d]=pref[i]; int c=cnt[i]; inv[d]=1.0f/(float)(c>0?c:1); }
  }
  __syncthreads();
  for(int i=lo+t;i<hi;i+=256){
    ull v=tmp8[i];
    int ld=(int)(v>>32)-nb;
    int r=atomicAdd(&cur2[ld],1);
    col[r]=(int)(v&0xffffffffu);
  }
}

// ===== fallback build =====
__global__ void count_kernel(const int* dst, int* cnt){
  int e = blockIdx.x*256 + threadIdx.x;
  if(e < NE) atomicAdd(&cnt[dst[e]], 1);
}
__global__ void scan_kernel(const int* cnt, int* off, int* cur, float* inv){
  __shared__ int part[1024];
  int t = threadIdx.x;
  const int CH = (NND + 1023)/1024;
  int lo = t*CH, hi = lo+CH; if(hi>NND) hi=NND;
  int s=0;
  for(int i=lo;i<hi;++i) s += cnt[i];
  part[t]=s;
  __syncthreads();
  if(t==0){ int run=0; for(int i=0;i<1024;++i){ int v=part[i]; part[i]=run; run+=v; } }
  __syncthreads();
  int run = part[t];
  for(int i=lo;i<hi;++i){
    off[i]=run; cur[i]=run;
    int c=cnt[i];
    inv[i]=1.0f/(float)(c>0?c:1);
    run+=c;
  }
  if(t==0) off[NND]=NE;
}
__global__ void fill_kernel(const int* dst, int* cur, int* col){
  int e = blockIdx.x*256 + threadIdx.x;
  if(e < NE){
    int d = dst[e];
    int slot = atomicAdd(&cur[d],1);
    col[slot] = e;
  }
}

// wave odd-even sort of each CSR segment
__global__ void __launch_bounds__(256) sortseg_wave_kernel(const int* off, int* col){
  int t=threadIdx.x, lane=t&63, w=t>>6;
  int node = blockIdx.x*4 + w;
  if(node>=NND) return;
  int lo=off[node], hi=off[node+1];
  int deg=hi-lo;
  if(deg<=1) return;
  if(deg<=64){
    int v = (lane<deg)? col[lo+lane] : 0x7fffffff;
    for(int p=0;p<64;++p){
      int partner;
      if((p&1)==0) partner = lane^1;
      else partner = (lane==0||lane==63)? lane : ((lane&1)? lane+1 : lane-1);
      int pv = __shfl(v, partner, 64);
      if(partner>lane) v = v<pv? v:pv;
      else if(partner<lane) v = v>pv? v:pv;
    }
    if(lane<deg) col[lo+lane]=v;
  } else if(lane==0){
    for(int i=lo+1;i<hi;++i){
      int v=col[i]; int j=i-1;
      while(j>=lo && col[j]>v){ col[j+1]=col[j]; --j; }
      col[j+1]=v;
    }
  }
}

// order-preserving 16-deep batched gather, 64-wide (FP order = sequential loop)
__device__ __forceinline__ float gather_seq(const float* __restrict__ src, int S, int d,
    const int* __restrict__ col, int lo, int hi, int lane){
  float acc=0.f;
  int deg=hi-lo, base=0;
  while(base<deg){
    int rem=deg-base; int cw = rem<64?rem:64;
    int cv = col[lo+base+ (lane<cw?lane:cw-1)];
    for(int k=0;k<cw;k+=16){
      int m=cw-k;
      float v[16];
#pragma unroll
      for(int j=0;j<16;++j){
        int q = (j<m)? k+j : k;
        int s = __shfl(cv,q,64)>>5;
        v[j] = src[(size_t)s*S+d];
      }
#pragma unroll
      for(int j=0;j<16;++j) if(j<m) acc += v[j];
    }
    base+=cw;
  }
  return acc;
}

// same, 32-wide (half-wave), FP order identical to sequential loop
__device__ __forceinline__ float gather_seq32(const float* __restrict__ src, int S, int d,
    const int* __restrict__ col, int lo, int hi, int l){
  float acc=0.f;
  int deg=hi-lo, base=0;
  while(base<deg){
    int rem=deg-base; int cw = rem<32?rem:32;
    int cv = col[lo+base+ (l<cw?l:cw-1)];
    for(int k=0;k<cw;k+=16){
      int m=cw-k;
      float v[16];
#pragma unroll
      for(int j=0;j<16;++j){
        int q = (j<m)? k+j : k;
        int s = __shfl(cv,q,32)>>5;
        v[j] = src[(size_t)s*S+d];
      }
#pragma unroll
      for(int j=0;j<16;++j) if(j<m) acc += v[j];
    }
    base+=cw;
  }
  return acc;
}

// h1base = leaky_relu(agg@Wl1.T + bl1 + x@Wr1.T); 512 threads, 8 nodes/block
__global__ void __launch_bounds__(512) sage1base_kernel(const float* __restrict__ x,
    const int* __restrict__ off, const int* __restrict__ col,
    const float* __restrict__ inv, const float* __restrict__ Wl,
    const float* __restrict__ bl, const float* __restrict__ Wr,
    float* __restrict__ h1base){
  __shared__ float sWlT[DD0*HH], sWrT[DD0*HH];
  __shared__ float sA[8][DD0], sX[8][DD0];
  int t=threadIdx.x, lane=t&63, w=t>>6;
  for(int j=t;j<HH*DD0;j+=512){
    int k=j>>5, h=j&31;
    sWlT[j]=Wl[h*DD0+k]; sWrT[j]=Wr[h*DD0+k];
  }
  int node=blockIdx.x*8+w;
  int lo=off[node], hi=off[node+1];
  float acc=gather_seq(x,DD0,lane,col,lo,hi,lane);
  acc *= inv[node];
  sA[w][lane]=acc;
  sX[w][lane]=x[(size_t)node*DD0+lane];
  __syncthreads();
  if(lane<HH){
    float s1=0.f, s2=0.f;
    for(int k=0;k<DD0;++k){
      s1 += sA[w][k]*sWlT[k*HH+lane];
      s2 += sX[w][k]*sWrT[k*HH+lane];
    }
    float v=s1+bl[lane]+s2;
    v = (v>=0.f) ? v : 0.01f*v;
    h1base[(size_t)node*HH+lane]=v;
  }
}

__global__ void __launch_bounds__(256) mask_kernel(const float* __restrict__ h1base,
    const uint32_t* __restrict__ keys, int cid, float* __restrict__ h1){
  int j = blockIdx.x*256 + threadIdx.x;
  if(j < NND*HH){
    uint32_t bits = xorbits(keys[cid*4+0],keys[cid*4+1],(uint32_t)j);
    float v = h1base[j];
    h1[j] = ((bits>>31)==0u) ? 2.f*v : 0.f;
  }
}

// full sage1 (fallback tiers)
__global__ void __launch_bounds__(256) sage1_kernel(const float* __restrict__ x,
    const int* __restrict__ off, const int* __restrict__ col,
    const float* __restrict__ inv, const float* __restrict__ Wl,
    const float* __restrict__ bl, const float* __restrict__ Wr,
    const uint32_t* __restrict__ keys, int cid, float* __restrict__ h1o){
  __shared__ float sWlT[DD0*HH], sWrT[DD0*HH];
  __shared__ float sA[4][DD0], sX[4][DD0];
  int t=threadIdx.x, lane=t&63, w=t>>6;
  for(int j=t;j<HH*DD0;j+=256){
    int k=j>>5, h=j&31;
    sWlT[j]=Wl[h*DD0+k]; sWrT[j]=Wr[h*DD0+k];
  }
  int node=blockIdx.x*4+w;
  int lo=off[node], hi=off[node+1];
  float acc=gather_seq(x,DD0,lane,col,lo,hi,lane);
  acc *= inv[node];
  sA[w][lane]=acc;
  sX[w][lane]=x[(size_t)node*DD0+lane];
  __syncthreads();
  if(lane<HH){
    float s1=0.f, s2=0.f;
    for(int k=0;k<DD0;++k){
      s1 += sA[w][k]*sWlT[k*HH+lane];
      s2 += sX[w][k]*sWrT[k*HH+lane];
    }
    float v=s1+bl[lane]+s2;
    v = (v>=0.f) ? v : 0.01f*v;
    uint32_t j=(uint32_t)(node*HH+lane);
    uint32_t bits = xorbits(keys[cid*4+0],keys[cid*4+1],j);
    v = ((bits>>31)==0u) ? 2.f*v : 0.f;
    h1o[(size_t)node*HH+lane]=v;
  }
}

__device__ __forceinline__ float g_row_core(int n, int lane,
    const float* __restrict__ h1, const int* __restrict__ off,
    const int* __restrict__ col, const float* __restrict__ inv,
    const float* __restrict__ sWlT, const float* __restrict__ sWrT,
    const float* __restrict__ bl2, uint32_t k2a, uint32_t k2b){
  int lo=off[n], hi=off[n+1];
  int d=lane&31;
  float acc=gather_seq(h1,HH,d,col,lo,hi,lane);
  float aggd = acc*inv[n];
  float hd   = h1[(size_t)n*HH+d];
  float s1=0.f, s2=0.f;
  for(int k=0;k<HH;++k){
    float ak=__shfl(aggd,k,64);
    float hk=__shfl(hd,k,64);
    s1 += ak*sWlT[k*DD2+lane];
    s2 += hk*sWrT[k*DD2+lane];
  }
  float v=s1+bl2[lane]+s2;
  uint32_t j=(uint32_t)n*64u+(uint32_t)lane;
  uint32_t bits = xorbits(k2a,k2b,j);
  v = ((bits>>31)==0u) ? 2.f*v : 0.f;
  float ss=v*v;
  for(int m=1;m<64;m<<=1) ss += __shfl_xor(ss,m,64);
  return v/fmaxf(sqrtf(ss),1e-12f);
}

// TWO g-rows per wave: half-wave per row, each lane computes output dims l and l+32.
// Norm = T32(dims0-31) + T32(dims32-63): bit-identical to the old 64-lane butterfly.
__global__ void __launch_bounds__(512) grows2_kernel(
    const float* __restrict__ h1, const int* __restrict__ off,
    const int* __restrict__ col, const float* __restrict__ inv,
    const float* __restrict__ Wl2, const float* __restrict__ bl2,
    const float* __restrict__ Wr2, const uint32_t* __restrict__ keys, int cid,
    const int* __restrict__ users, const int* __restrict__ pid_arr,
    const int* __restrict__ adj, float* __restrict__ rowbuf){
  __shared__ float sWlT[HH*DD2], sWrT[HH*DD2];
  int t=threadIdx.x, lane=t&63, w=t>>6;
  int half=lane>>5, l=lane&31;
  for(int j=t;j<HH*DD2;j+=512){
    int k=j>>6, d=j&63;
    sWlT[j]=Wl2[d*HH+k]; sWrT[j]=Wr2[d*HH+k];
  }
  __syncthreads();
  int wg = blockIdx.x*16 + w*2 + half;            // grid*16 == BB*NROWS
  int b = wg/NROWS, r = wg - b*NROWS;
  int pid = pid_arr[b];
  int node = (r==0)? users[b] : ((r==1)? pid : adj[(size_t)pid*KN + (r-2)]);
  uint32_t k2a=keys[cid*4+2], k2b=keys[cid*4+3];
  int lo=off[node], hi=off[node+1];
  float acc = gather_seq32(h1,HH,l,col,lo,hi,l);
  float aggd = acc*inv[node];
  float hd   = h1[(size_t)node*HH+l];
  float s1a=0.f,s2a=0.f,s1b=0.f,s2b=0.f;
  for(int k=0;k<HH;++k){
    float ak=__shfl(aggd,k,32);
    float hk=__shfl(hd,k,32);
    s1a += ak*sWlT[k*DD2+l];      s2a += hk*sWrT[k*DD2+l];
    s1b += ak*sWlT[k*DD2+l+32];   s2b += hk*sWrT[k*DD2+l+32];
  }
  float va=s1a+bl2[l]+s2a;
  float vb=s1b+bl2[l+32]+s2b;
  uint32_t ja=(uint32_t)node*64u+(uint32_t)l;
  va = ((xorbits(k2a,k2b,ja)>>31)==0u)     ? 2.f*va : 0.f;
  vb = ((xorbits(k2a,k2b,ja+32u)>>31)==0u) ? 2.f*vb : 0.f;
  float ssa=va*va, ssb=vb*vb;
  for(int m=1;m<32;m<<=1){ ssa += __shfl_xor(ssa,m,32); ssb += __shfl_xor(ssb,m,32); }
  float nr=fmaxf(sqrtf(ssa+ssb),1e-12f);
  rowbuf[(size_t)wg*DD2 + l]      = va/nr;
  rowbuf[(size_t)wg*DD2 + l + 32] = vb/nr;
}

__global__ void __launch_bounds__(64) sel1_kernel(
    const float* __restrict__ rowbuf,
    const int* __restrict__ users, const int* __restrict__ pid_arr,
    const int* __restrict__ adj, int* __restrict__ oh_out, float* __restrict__ l1_out){
  int b=blockIdx.x, t=threadIdx.x;
  __shared__ float wsh[DD2];
  __shared__ float ps[KN];
  const float* rb = rowbuf + (size_t)b*NROWS*DD2;
  wsh[t] = rb[t]*rb[DD2+t];
  __syncthreads();
  if(t<KN){
    float p=0.f;
    const float* rr = rb + (size_t)(2+t)*DD2;
    for(int d=0;d<DD2;++d) p += rr[d]*wsh[d];
    ps[t]=p;
  }
  __syncthreads();
  if(t==0){
    float m=ps[0]; for(int k=1;k<KN;++k) m=fmaxf(m,ps[k]);
    float s=0.f;  for(int k=0;k<KN;++k) s += expf(ps[k]-m);
    int best=0; float bv=ps[0];
    for(int k=1;k<KN;++k) if(ps[k]>bv){bv=ps[k];best=k;}
    oh_out[b]=adj[(size_t)pid_arr[b]*KN+best];
    l1_out[b]=(ps[best]-m)-logf(s);
  }
}

__global__ void __launch_bounds__(64) sel2_kernel(
    const float* __restrict__ rowbuf, const uint32_t* __restrict__ keys, int kf_idx,
    const int* __restrict__ users, const int* __restrict__ oh,
    const int* __restrict__ adj,
    const float* __restrict__ du, const float* __restrict__ di,
    const int* __restrict__ train, const int* __restrict__ neg,
    const float* __restrict__ l1, int round,
    int* __restrict__ gneg_out, float* __restrict__ out){
  int b=blockIdx.x, t=threadIdx.x;
  __shared__ float wsh[DD2];
  __shared__ float ps[KN], lps[KN], rk[KN];
  __shared__ int nid[KN], cand[KN];
  __shared__ float msh[2];
  const float* rb = rowbuf + (size_t)b*NROWS*DD2;
  wsh[t] = rb[t]*rb[DD2+t];
  __syncthreads();
  if(t<KN){
    float p=0.f;
    const float* rr = rb + (size_t)(2+t)*DD2;
    for(int d=0;d<DD2;++d) p += rr[d]*wsh[d];
    ps[t]=p;
  }
  __syncthreads();
  if(t==0){
    float m=ps[0]; for(int k=1;k<KN;++k) m=fmaxf(m,ps[k]);
    float s=0.f;  for(int k=0;k<KN;++k) s += expf(ps[k]-m);
    msh[0]=m; msh[1]=logf(s);
    for(int k=0;k<KN;++k) nid[k]=k;
    for(int i=1;i<KN;++i){
      int v=nid[i]; float pv=ps[v]; int j=i-1;
      while(j>=0 && ps[nid[j]]>pv){ nid[j+1]=nid[j]; --j; }
      nid[j+1]=v;
    }
  }
  __syncthreads();
  if(t<KN){
    int n=t, c=adj[(size_t)oh[b]*KN + nid[n]];
    if(c<0 || c>49999){
      uint32_t i0=(uint32_t)(b*KN+n);
      const uint32_t* fk = keys + 16 + kf_idx*4;
      uint32_t hb = xorbits(fk[0], fk[1], i0);
      uint32_t lb = xorbits(fk[2], fk[3], i0);
      c=(int)(((hb%50000u)*17296u + (lb%50000u))%50000u);
    }
    cand[n]=c;
    lps[n]=(ps[nid[n]]-msh[0])-msh[1];
    int u=users[b];
    float rr=0.f;
    for(int d=0;d<DD2;++d) rr += du[(size_t)u*DD2+d]*di[(size_t)c*DD2+d];
    rk[n]=rr;
  }
  __syncthreads();
  if(t==0){
    int best=0; float bv=rk[0];
    for(int n=1;n<KN;++n) if(rk[n]>bv){bv=rk[n];best=n;}
    int gn=cand[best]; float lsel=lps[best];
    bool it=false;
    for(int t2=0;t2<TT;++t2) if(train[(size_t)b*TT+t2]==gn){it=true;break;}
    if(it) gn=neg[b];
    gneg_out[b]=gn;
    out[b*2+round]        = (float)gn;
    out[BB*2 + b*2+round] = l1[b]+lsel;
  }
}

// ===== fallback fused steps (tier 0) =====
__global__ void __launch_bounds__(256) fstep1_kernel(
    const float* __restrict__ h1, const int* __restrict__ off,
    const int* __restrict__ col, const float* __restrict__ inv,
    const float* __restrict__ Wl2, const float* __restrict__ bl2,
    const float* __restrict__ Wr2, const uint32_t* __restrict__ keys, int cid,
    const int* __restrict__ users, const int* __restrict__ pid_arr,
    const int* __restrict__ adj, int* __restrict__ oh_out, float* __restrict__ l1_out){
  __shared__ float sWlT[HH*DD2], sWrT[HH*DD2];
  __shared__ float rows[2+KN][DD2+1];
  __shared__ int nds[2+KN];
  __shared__ float ps[KN];
  int t=threadIdx.x, lane=t&63, w=t>>6, b=blockIdx.x;
  for(int j=t;j<HH*DD2;j+=256){
    int k=j>>6, d=j&63;
    sWlT[j]=Wl2[d*HH+k]; sWrT[j]=Wr2[d*HH+k];
  }
  if(t==0){ nds[0]=users[b]; nds[1]=pid_arr[b]; }
  if(t>=2 && t<2+KN) nds[t]=adj[(size_t)pid_arr[b]*KN + (t-2)];
  __syncthreads();
  uint32_t k2a=keys[cid*4+2], k2b=keys[cid*4+3];
  for(int r=w; r<2+KN; r+=4)
    rows[r][lane]=g_row_core(nds[r],lane,h1,off,col,inv,sWlT,sWrT,bl2,k2a,k2b);
  __syncthreads();
  if(t<KN){
    float p=0.f;
    for(int d=0;d<DD2;++d) p += rows[2+t][d]*(rows[0][d]*rows[1][d]);
    ps[t]=p;
  }
  __syncthreads();
  if(t==0){
    float m=ps[0]; for(int k=1;k<KN;++k) m=fmaxf(m,ps[k]);
    float s=0.f;  for(int k=0;k<KN;++k) s += expf(ps[k]-m);
    int best=0; float bv=ps[0];
    for(int k=1;k<KN;++k) if(ps[k]>bv){bv=ps[k];best=k;}
    oh_out[b]=nds[2+best];
    l1_out[b]=(ps[best]-m)-logf(s);
  }
}

__global__ void __launch_bounds__(256) fstep2_kernel(
    const float* __restrict__ h1, const int* __restrict__ off,
    const int* __restrict__ col, const float* __restrict__ inv,
    const float* __restrict__ Wl2, const float* __restrict__ bl2,
    const float* __restrict__ Wr2, const uint32_t* __restrict__ keys,
    int cid, int kf_idx,
    const int* __restrict__ users, const int* __restrict__ oh,
    const int* __restrict__ adj,
    const float* __restrict__ du, const float* __restrict__ di,
    const int* __restrict__ train, const int* __restrict__ neg,
    const float* __restrict__ l1, int round,
    int* __restrict__ gneg_out, float* __restrict__ out){
  __shared__ float sWlT[HH*DD2], sWrT[HH*DD2];
  __shared__ float rows[2+KN][DD2+1];
  __shared__ int nds[2+KN];
  __shared__ float ps[KN], lps[KN], rk[KN];
  __shared__ int nid[KN], cand[KN];
  __shared__ float msh[2];
  int t=threadIdx.x, lane=t&63, w=t>>6, b=blockIdx.x;
  for(int j=t;j<HH*DD2;j+=256){
    int k=j>>6, d=j&63;
    sWlT[j]=Wl2[d*HH+k]; sWrT[j]=Wr2[d*HH+k];
  }
  if(t==0){ nds[0]=users[b]; nds[1]=oh[b]; }
  if(t>=2 && t<2+KN) nds[t]=adj[(size_t)oh[b]*KN + (t-2)];
  __syncthreads();
  uint32_t k2a=keys[cid*4+2], k2b=keys[cid*4+3];
  for(int r=w; r<2+KN; r+=4)
    rows[r][lane]=g_row_core(nds[r],lane,h1,off,col,inv,sWlT,sWrT,bl2,k2a,k2b);
  __syncthreads();
  if(t<KN){
    float p=0.f;
    for(int d=0;d<DD2;++d) p += rows[2+t][d]*(rows[0][d]*rows[1][d]);
    ps[t]=p;
  }
  __syncthreads();
  if(t==0){
    float m=ps[0]; for(int k=1;k<KN;++k) m=fmaxf(m,ps[k]);
    float s=0.f;  for(int k=0;k<KN;++k) s += expf(ps[k]-m);
    msh[0]=m; msh[1]=logf(s);
    for(int k=0;k<KN;++k) nid[k]=k;
    for(int i=1;i<KN;++i){
      int v=nid[i]; float pv=ps[v]; int j=i-1;
      while(j>=0 && ps[nid[j]]>pv){ nid[j+1]=nid[j]; --j; }
      nid[j+1]=v;
    }
  }
  __syncthreads();
  if(t<KN){
    int n=t, c=nds[2+nid[n]];
    if(c<0 || c>49999){
      uint32_t i0=(uint32_t)(b*KN+n);
      const uint32_t* fk = keys + 16 + kf_idx*4;
      uint32_t hb = xorbits(fk[0], fk[1], i0);
      uint32_t lb = xorbits(fk[2], fk[3], i0);
      c=(int)(((hb%50000u)*17296u + (lb%50000u))%50000u);
    }
    cand[n]=c;
    lps[n]=(ps[nid[n]]-msh[0])-msh[1];
    int u=nds[0];
    float rr=0.f;
    for(int d=0;d<DD2;++d) rr += du[(size_t)u*DD2+d]*di[(size_t)c*DD2+d];
    rk[n]=rr;
  }
  __syncthreads();
  if(t==0){
    int best=0; float bv=rk[0];
    for(int n=1;n<KN;++n) if(rk[n]>bv){bv=rk[n];best=n;}
    int gn=cand[best]; float lsel=lps[best];
    bool it=false;
    for(int t2=0;t2<TT;++t2) if(train[(size_t)b*TT+t2]==gn){it=true;break;}
    if(it) gn=neg[b];
    gneg_out[b]=gn;
    out[b*2+round]        = (float)gn;
    out[BB*2 + b*2+round] = l1[b]+lsel;
  }
}

extern "C" void kernel_launch(void* const* d_in, const int* in_sizes, int n_in,
                              void* d_out, int out_size, void* d_ws, size_t ws_size,
                              hipStream_t stream) {
  const int*   users=(const int*)d_in[0];
  const int*   pos  =(const int*)d_in[1];
  const int*   neg  =(const int*)d_in[2];
  const int*   train=(const int*)d_in[3];
  const int*   adj  =(const int*)d_in[4];
  const int*   edge =(const int*)d_in[5];
  const float* ent  =(const float*)d_in[6];
  const float* Wl1  =(const float*)d_in[7];
  const float* bl1  =(const float*)d_in[8];
  const float* Wr1  =(const float*)d_in[9];
  const float* Wl2  =(const float*)d_in[10];
  const float* bl2  =(const float*)d_in[11];
  const float* Wr2  =(const float*)d_in[12];
  const float* du   =(const float*)d_in[13];
  const float* di   =(const float*)d_in[14];
  float* out=(float*)d_out;

  char* wsb=(char*)d_ws;
  size_t o=0;
  auto alloc=[&](size_t n)->char*{ char* p=wsb+o; o=(o+n+255)&~(size_t)255; return p; };
  uint32_t* keys=(uint32_t*)alloc(32*4);
  int*   bcnt=(int*)alloc((size_t)(NBUK+1)*4);
  int*   boff=(int*)alloc((size_t)(NBUK+1)*4);
  int*   bcur=(int*)alloc((size_t)NBUK*4);
  int*   ohb=(int*)alloc((size_t)BB*4);
  float* l1b=(float*)alloc((size_t)BB*4);
  int*   g1b=(int*)alloc((size_t)BB*4);
  int*   g2b=(int*)alloc((size_t)BB*4);
  int*   cnt=(int*)alloc((size_t)NND*4);
  int*   off=(int*)alloc((size_t)(NND+1)*4);
  int*   cur=(int*)alloc((size_t)NND*4);
  float* inv=(float*)alloc((size_t)NND*4);
  int*   col=(int*)alloc((size_t)NE*4);
  float* h1 =(float*)alloc((size_t)NND*HH*4);
  float* rowbuf=(float*)alloc((size_t)BB*NROWS*DD2*4);
  size_t o_rowbuf = o;
  float* h1base=(float*)alloc((size_t)NND*HH*4);
  int tier = (ws_size >= o) ? 2 : ((ws_size >= o_rowbuf) ? 1 : 0);
  ull* tmp8 = (ull*)rowbuf;   // aliases rowbuf+h1base; build precedes their use

  keys_kernel<<<1,64,0,stream>>>(keys,bcnt);

  if(tier==2){
    bcount_kernel<<<512,256,0,stream>>>(edge,bcnt);
    bscan_kernel<<<1,64,0,stream>>>(bcnt,boff,bcur,off);
    bscatter_kernel<<<512,256,0,stream>>>(edge,bcur,tmp8);
    bucket_csr_kernel<<<NBUK,256,0,stream>>>(boff,tmp8,off,inv,col);
  } else {
    hipMemsetAsync(cnt,0,(size_t)NND*4,stream);
    count_kernel<<<NE/256,256,0,stream>>>(edge,cnt);
    scan_kernel<<<1,1024,0,stream>>>(cnt,off,cur,inv);
    fill_kernel<<<NE/256,256,0,stream>>>(edge,cur,col);
  }
  sortseg_wave_kernel<<<NND/4,256,0,stream>>>(off,col);

  const int GROWS2_GRID = BB*NROWS/16;   // 4352
  const int MASK_GRID   = (NND*HH+255)/256;

  if(tier==2){
    sage1base_kernel<<<NND/8,512,0,stream>>>(ent,off,col,inv,Wl1,bl1,Wr1,h1base);
    for(int r=0;r<2;++r){
      const int* pid = (r==0)? pos : g1b;
      int cidA=2*r, cidB=2*r+1;
      mask_kernel<<<MASK_GRID,256,0,stream>>>(h1base,keys,cidA,h1);
      grows2_kernel<<<GROWS2_GRID,512,0,stream>>>(h1,off,col,inv,Wl2,bl2,Wr2,keys,cidA,
                                                  users,pid,adj,rowbuf);
      sel1_kernel<<<BB,64,0,stream>>>(rowbuf,users,pid,adj,ohb,l1b);
      mask_kernel<<<MASK_GRID,256,0,stream>>>(h1base,keys,cidB,h1);
      grows2_kernel<<<GROWS2_GRID,512,0,stream>>>(h1,off,col,inv,Wl2,bl2,Wr2,keys,cidB,
                                                  users,ohb,adj,rowbuf);
      sel2_kernel<<<BB,64,0,stream>>>(rowbuf,keys,r,users,ohb,adj,du,di,train,neg,l1b,r,
                                      (r==0)?g1b:g2b,out);
    }
  } else if(tier==1){
    for(int r=0;r<2;++r){
      const int* pid = (r==0)? pos : g1b;
      int cidA=2*r, cidB=2*r+1;
      sage1_kernel<<<NND/4,256,0,stream>>>(ent,off,col,inv,Wl1,bl1,Wr1,keys,cidA,h1);
      grows2_kernel<<<GROWS2_GRID,512,0,stream>>>(h1,off,col,inv,Wl2,bl2,Wr2,keys,cidA,
                                                  users,pid,adj,rowbuf);
      sel1_kernel<<<BB,64,0,stream>>>(rowbuf,users,pid,adj,ohb,l1b);
      sage1_kernel<<<NND/4,256,0,stream>>>(ent,off,col,inv,Wl1,bl1,Wr1,keys,cidB,h1);
      grows2_kernel<<<GROWS2_GRID,512,0,stream>>>(h1,off,col,inv,Wl2,bl2,Wr2,keys,cidB,
                                                  users,ohb,adj,rowbuf);
      sel2_kernel<<<BB,64,0,stream>>>(rowbuf,keys,r,users,ohb,adj,du,di,train,neg,l1b,r,
                                      (r==0)?g1b:g2b,out);
    }
  } else {
    for(int r=0;r<2;++r){
      const int* pid = (r==0)? pos : g1b;
      int cidA=2*r, cidB=2*r+1;
      sage1_kernel<<<NND/4,256,0,stream>>>(ent,off,col,inv,Wl1,bl1,Wr1,keys,cidA,h1);
      fstep1_kernel<<<BB,256,0,stream>>>(h1,off,col,inv,Wl2,bl2,Wr2,keys,cidA,
                                         users,pid,adj,ohb,l1b);
      sage1_kernel<<<NND/4,256,0,stream>>>(ent,off,col,inv,Wl1,bl1,Wr1,keys,cidB,h1);
      fstep2_kernel<<<BB,256,0,stream>>>(h1,off,col,inv,Wl2,bl2,Wr2,keys,cidB,r,
                                         users,ohb,adj,du,di,train,neg,l1b,r,
                                         (r==0)?g1b:g2b,out);
    }
  }
}